// Round 1
// baseline (233.432 us; speedup 1.0000x reference)
//
#include <hip/hip_runtime.h>
#include <stdint.h>

// Problem constants
#define NF 4096     // front tokens (64x64)
#define NS 1024     // sat tokens
#define MD 512      // model dim (8 heads x 64)
#define HD 64
#define DA 96       // augmented attention K-dim: 64 main + 16 geo + 16 zero pad
#define GHID 128
#define GHD 16

typedef unsigned short u16;
typedef __attribute__((ext_vector_type(8))) short bf8v;   // 8 bf16 (4 VGPRs)
typedef __attribute__((ext_vector_type(4))) float f4v;

__device__ __forceinline__ u16 f2bf(float f) {
  union { float f; unsigned u; } v; v.f = f;
  unsigned r = (v.u + 0x7FFF + ((v.u >> 16) & 1)) >> 16;   // RNE
  return (u16)r;
}

__device__ __forceinline__ f4v mfma16(bf8v a, bf8v b, f4v c) {
  return __builtin_amdgcn_mfma_f32_16x16x32_bf16(a, b, c, 0, 0, 0);
}

__device__ __forceinline__ bf8v pack2(float4 v0, float4 v1) {
  bf8v p;
  p[0] = (short)f2bf(v0.x); p[1] = (short)f2bf(v0.y);
  p[2] = (short)f2bf(v0.z); p[3] = (short)f2bf(v0.w);
  p[4] = (short)f2bf(v1.x); p[5] = (short)f2bf(v1.y);
  p[6] = (short)f2bf(v1.z); p[7] = (short)f2bf(v1.w);
  return p;
}

// ---------------- small-K first MLP layers: out = silu(in @ w^T + b) ----------------
__global__ void k_silu_lin(const float* __restrict__ in, const float* __restrict__ w,
                           const float* __restrict__ b, float* __restrict__ out,
                           int N, int M, int K) {
  int idx = blockIdx.x * 256 + threadIdx.x;
  if (idx >= N * M) return;
  int n = idx / M, m = idx - n * M;
  float acc = b[m];
  for (int k = 0; k < K; ++k) acc += in[n * K + k] * w[m * K + k];
  out[idx] = acc / (1.f + __expf(-acc));
}

// ---------------- LayerNorm: out = LN(in1 + bias [+ in2]) * g + beta ----------------
__global__ void k_ln(const float* __restrict__ in1, const float* __restrict__ bias,
                     const float* __restrict__ in2, const float* __restrict__ g,
                     const float* __restrict__ beta, float* __restrict__ out, int D) {
  int row = blockIdx.x, tid = threadIdx.x;
  __shared__ float rs[8], rq[8];
  float s = 0.f, q = 0.f;
  for (int i = tid; i < D; i += 256) {
    float x = in1[row * D + i] + bias[i];
    if (in2) x += in2[row * D + i];
    s += x; q += x * x;
  }
  for (int m = 32; m; m >>= 1) { s += __shfl_down(s, m); q += __shfl_down(q, m); }
  if ((tid & 63) == 0) { rs[tid >> 6] = s; rq[tid >> 6] = q; }
  __syncthreads();
  if (tid == 0) {
    float a = 0.f, c = 0.f;
    for (int i = 0; i < 4; ++i) { a += rs[i]; c += rq[i]; }
    rs[4] = a; rq[4] = c;
  }
  __syncthreads();
  float mean = rs[4] / D;
  float var = rq[4] / D - mean * mean;
  float rstd = rsqrtf(var + 1e-5f);
  for (int i = tid; i < D; i += 256) {
    float x = in1[row * D + i] + bias[i];
    if (in2) x += in2[row * D + i];
    out[row * D + i] = (x - mean) * rstd * g[i] + beta[i];
  }
}

// ---------------- bf16 MFMA GEMM: out[M][N] = A . W^T ----------------
// A: TA ? [K][M] : [M][K] row-major f32 (TA=true fuses the front_feat transpose)
// W: [N][K] row-major f32. M%64==0, N%64==0, K%32==0.
template <bool TA>
__global__ __launch_bounds__(256) void k_gemm(const float* __restrict__ A,
                                              const float* __restrict__ W,
                                              float* __restrict__ out,
                                              int M, int N, int K) {
  __shared__ u16 sA[64][40];   // +8 pad: 80B row stride, 16B aligned, <=2-way banks
  __shared__ u16 sB[64][40];
  const int m0 = blockIdx.x * 64, n0 = blockIdx.y * 64;
  const int tid = threadIdx.x, w = tid >> 6, lane = tid & 63;
  const int l16 = lane & 15, lh = lane >> 4;
  f4v acc[4];
#pragma unroll
  for (int j = 0; j < 4; ++j) acc[j] = (f4v){0.f, 0.f, 0.f, 0.f};

  for (int k0 = 0; k0 < K; k0 += 32) {
    if (!TA) {
      int r = tid >> 2, ko = (tid & 3) * 8;
      const float* src = A + (size_t)(m0 + r) * K + k0 + ko;
      float4 v0 = *(const float4*)src, v1 = *(const float4*)(src + 4);
      *(bf8v*)&sA[r][ko] = pack2(v0, v1);
    } else {
      int kk = tid >> 3, mo = (tid & 7) * 8;
      const float* src = A + (size_t)(k0 + kk) * M + m0 + mo;
      float4 v0 = *(const float4*)src, v1 = *(const float4*)(src + 4);
      float t[8] = {v0.x, v0.y, v0.z, v0.w, v1.x, v1.y, v1.z, v1.w};
#pragma unroll
      for (int i = 0; i < 8; ++i) sA[mo + i][kk] = f2bf(t[i]);
    }
    {
      int r = tid >> 2, ko = (tid & 3) * 8;
      const float* src = W + (size_t)(n0 + r) * K + k0 + ko;
      float4 v0 = *(const float4*)src, v1 = *(const float4*)(src + 4);
      *(bf8v*)&sB[r][ko] = pack2(v0, v1);
    }
    __syncthreads();
    bf8v a = *(const bf8v*)&sA[w * 16 + l16][lh * 8];
#pragma unroll
    for (int j = 0; j < 4; ++j) {
      bf8v b = *(const bf8v*)&sB[j * 16 + l16][lh * 8];
      acc[j] = mfma16(a, b, acc[j]);
    }
    __syncthreads();
  }
  const int rr = m0 + w * 16 + (lh << 2);
#pragma unroll
  for (int j = 0; j < 4; ++j)
#pragma unroll
    for (int r = 0; r < 4; ++r)
      out[(size_t)(rr + r) * N + n0 + j * 16 + l16] = acc[j][r];
}

// ---------------- build augmented Q/K (bias + 2D GeoRoPE + geo head, bf16) ----------------
// aug[h][n][0:64]  = rope(lin[n, h*64: ] + bl) * sc_main
// aug[h][n][64:80] = (glin[n, h*16: ] + bg) * sc_geo ; [80:96] = 0
__global__ void k_qk_prep(const float* __restrict__ lin, const float* __restrict__ bl,
                          const float* __restrict__ glin, const float* __restrict__ bg,
                          const float* __restrict__ xy, u16* __restrict__ aug,
                          int N, float sc_main, float sc_geo) {
  int gid = blockIdx.x * 4 + (threadIdx.x >> 6);   // one wave = one (n,h)
  int lane = threadIdx.x & 63;
  int n = gid >> 3, h = gid & 7;
  if (n >= N) return;
  float val = lin[(size_t)n * MD + h * HD + lane] + bl[h * HD + lane];
  float part = __shfl_xor(val, 8);
  float outv = val;
  if (lane < 32) {
    // dims [0,16): x-axis, [16,32): y-axis; pairs (d, d^8); half=8
    float coord = (lane < 16) ? xy[n * 2] : xy[n * 2 + 1];
    int j = lane & 7;
    float th = coord * __expf(-(float)j * 1.1512925465f);   // 10000^(-j/8)
    float sn, cs;
    __sincosf(th, &sn, &cs);
    outv = ((lane & 8) == 0) ? (val * cs - part * sn) : (part * sn + val * cs);
  }
  u16* dst = aug + (size_t)(h * N + n) * DA;
  dst[lane] = f2bf(outv * sc_main);
  if (lane < GHD) {
    float gv = glin[(size_t)n * GHID + h * GHD + lane] + bg[h * GHD + lane];
    dst[64 + lane] = f2bf(gv * sc_geo);
  } else if (lane < 32) {
    dst[64 + lane] = 0;   // zero pad 80..95
  }
}

// ---------------- V transpose per head: VT[h][d][n] = bf16(v_lin[n][h*64+d] + bv) ----------------
__global__ void k_v_prep(const float* __restrict__ vlin, const float* __restrict__ bv,
                         u16* __restrict__ VT) {
  int idx = blockIdx.x * 256 + threadIdx.x;    // 8*64*1024 total
  int h = idx >> 16, rem = idx & 0xFFFF;
  int d = rem >> 10, n = rem & 1023;
  VT[idx] = f2bf(vlin[(size_t)n * MD + h * HD + d] + bv[h * HD + d]);
}

// ---------------- fused flash attention ----------------
// logits = Qaug . Kaug (scales pre-folded) - dist2(q_xy, k_xy), softmax over 1024 keys, @V
// block: 256 threads = 4 waves; wave owns 16 q-rows; Q-block 64 rows; key tiles of 64.
__global__ __launch_bounds__(256) void k_flash(const u16* __restrict__ Qa,
                                               const u16* __restrict__ Ka,
                                               const u16* __restrict__ VT,
                                               const float* __restrict__ qxy,
                                               const float* __restrict__ kxy,
                                               float* __restrict__ out) {
  const int h = blockIdx.y, qb = blockIdx.x;
  const int tid = threadIdx.x, w = tid >> 6, lane = tid & 63;
  const int l16 = lane & 15, lh = lane >> 4;
  __shared__ u16 sK[64][104];      // K-tile [64][96] (+8 pad)
  __shared__ u16 sV[64][72];       // V^T tile [64 d][64 k] (+8 pad)
  __shared__ u16 sP[4][16][72];    // per-wave P round-trip
  __shared__ float sXY[128];       // key xy pairs

  const int qrow = qb * 64 + w * 16 + l16;               // A-operand row
  bf8v qf[3];
#pragma unroll
  for (int c = 0; c < 3; ++c)
    qf[c] = *(const bf8v*)(Qa + (size_t)(h * NF + qrow) * DA + c * 32 + lh * 8);

  const int crow = qb * 64 + w * 16 + (lh << 2);         // C-layout row base
  float qx[4], qy[4];
#pragma unroll
  for (int r = 0; r < 4; ++r) {
    qx[r] = qxy[(crow + r) * 2];
    qy[r] = qxy[(crow + r) * 2 + 1];
  }
  float m_run[4], l_run[4];
  f4v accO[4];
#pragma unroll
  for (int r = 0; r < 4; ++r) { m_run[r] = -1e30f; l_run[r] = 0.f; }
#pragma unroll
  for (int d = 0; d < 4; ++d) accO[d] = (f4v){0.f, 0.f, 0.f, 0.f};

  for (int kt = 0; kt < NS / 64; ++kt) {
    const int kb = kt * 64;
#pragma unroll
    for (int i = 0; i < 3; ++i) {          // stage K tile: 64 rows x 96 = 768 16B-chunks
      int cid = tid + i * 256;
      int r = cid / 12, off = (cid % 12) * 8;
      *(bf8v*)&sK[r][off] = *(const bf8v*)(Ka + (size_t)(h * NS + kb + r) * DA + off);
    }
#pragma unroll
    for (int i = 0; i < 2; ++i) {          // stage V^T tile: 64 d x 64 k
      int cid = tid + i * 256;
      int d = cid >> 3, off = (cid & 7) * 8;
      *(bf8v*)&sV[d][off] = *(const bf8v*)(VT + (size_t)(h * HD + d) * NS + kb + off);
    }
    if (tid < 128) sXY[tid] = kxy[kb * 2 + tid];
    __syncthreads();

    // S = Qaug.Kaug - dist2  (C layout: row=(lh*4+r), col=j*16+l16)
    float p[4][4];
    float rmax[4] = {-1e30f, -1e30f, -1e30f, -1e30f};
#pragma unroll
    for (int j = 0; j < 4; ++j) {
      f4v s4 = (f4v){0.f, 0.f, 0.f, 0.f};
#pragma unroll
      for (int c = 0; c < 3; ++c) {
        bf8v kf = *(const bf8v*)&sK[j * 16 + l16][c * 32 + lh * 8];
        s4 = mfma16(qf[c], kf, s4);
      }
      float kx = sXY[(j * 16 + l16) * 2], ky = sXY[(j * 16 + l16) * 2 + 1];
#pragma unroll
      for (int r = 0; r < 4; ++r) {
        float dx = qx[r] - kx, dy = qy[r] - ky;
        float sv = s4[r] - dx * dx - dy * dy;
        p[j][r] = sv;
        rmax[r] = fmaxf(rmax[r], sv);
      }
    }
    // row reduce over the 16-lane group (cols), masks 1..8 stay in-group
#pragma unroll
    for (int r = 0; r < 4; ++r)
#pragma unroll
      for (int m = 1; m < 16; m <<= 1)
        rmax[r] = fmaxf(rmax[r], __shfl_xor(rmax[r], m));

    float mold[4], lsum[4];
#pragma unroll
    for (int r = 0; r < 4; ++r) {
      mold[r] = m_run[r];
      m_run[r] = fmaxf(m_run[r], rmax[r]);
      lsum[r] = 0.f;
    }
#pragma unroll
    for (int j = 0; j < 4; ++j)
#pragma unroll
      for (int r = 0; r < 4; ++r) {
        p[j][r] = __expf(p[j][r] - m_run[r]);
        lsum[r] += p[j][r];
      }
#pragma unroll
    for (int r = 0; r < 4; ++r)
#pragma unroll
      for (int m = 1; m < 16; m <<= 1)
        lsum[r] += __shfl_xor(lsum[r], m);
#pragma unroll
    for (int r = 0; r < 4; ++r) {
      float sc = __expf(mold[r] - m_run[r]);
      l_run[r] = l_run[r] * sc + lsum[r];
#pragma unroll
      for (int d = 0; d < 4; ++d) accO[d][r] *= sc;
    }
    // P -> LDS (C layout) then reread in A-operand layout
#pragma unroll
    for (int j = 0; j < 4; ++j)
#pragma unroll
      for (int r = 0; r < 4; ++r)
        sP[w][(lh << 2) + r][j * 16 + l16] = f2bf(p[j][r]);
    __syncthreads();
#pragma unroll
    for (int c = 0; c < 2; ++c) {
      bf8v pf = *(const bf8v*)&sP[w][l16][c * 32 + lh * 8];
#pragma unroll
      for (int d = 0; d < 4; ++d) {
        bf8v vf = *(const bf8v*)&sV[d * 16 + l16][c * 32 + lh * 8];
        accO[d] = mfma16(pf, vf, accO[d]);
      }
    }
    __syncthreads();   // protect sK/sV/sP before next stage
  }
#pragma unroll
  for (int d = 0; d < 4; ++d)
#pragma unroll
    for (int r = 0; r < 4; ++r)
      out[(size_t)(crow + r) * MD + h * HD + d * 16 + l16] = accO[d][r] / l_run[r];
}

extern "C" void kernel_launch(void* const* d_in, const int* in_sizes, int n_in,
                              void* d_out, int out_size, void* d_ws, size_t ws_size,
                              hipStream_t stream) {
  (void)in_sizes; (void)n_in; (void)out_size; (void)ws_size;
  const float* front_feat = (const float*)d_in[0];
  const float* bev_xy     = (const float*)d_in[1];
  const float* sat_tokens = (const float*)d_in[2];
  const float* sat_xy     = (const float*)d_in[3];
  const float* plucker    = (const float*)d_in[4];
  const float* pos_w1 = (const float*)d_in[5];
  const float* pos_b1 = (const float*)d_in[6];
  const float* pos_w2 = (const float*)d_in[7];
  const float* pos_b2 = (const float*)d_in[8];
  const float* fa_w   = (const float*)d_in[9];
  const float* fa_b   = (const float*)d_in[10];
  const float* fa_ln_g = (const float*)d_in[11];
  const float* fa_ln_b = (const float*)d_in[12];
  const float* qn_g   = (const float*)d_in[13];
  const float* qn_b   = (const float*)d_in[14];
  const float* sa_w   = (const float*)d_in[15];
  const float* sa_b   = (const float*)d_in[16];
  const float* sa_ln_g = (const float*)d_in[17];
  const float* sa_ln_b = (const float*)d_in[18];
  const float* wq = (const float*)d_in[19];
  const float* bq = (const float*)d_in[20];
  const float* wk = (const float*)d_in[21];
  const float* bk = (const float*)d_in[22];
  const float* wv = (const float*)d_in[23];
  const float* bv = (const float*)d_in[24];
  const float* plk_w1 = (const float*)d_in[25];
  const float* plk_b1 = (const float*)d_in[26];
  const float* plk_w2 = (const float*)d_in[27];
  const float* plk_b2 = (const float*)d_in[28];
  const float* sxy_w1 = (const float*)d_in[29];
  const float* sxy_b1 = (const float*)d_in[30];
  const float* sxy_w2 = (const float*)d_in[31];
  const float* sxy_b2 = (const float*)d_in[32];
  const float* gqn_g = (const float*)d_in[33];
  const float* gqn_b = (const float*)d_in[34];
  const float* gkn_g = (const float*)d_in[35];
  const float* gkn_b = (const float*)d_in[36];
  const float* wqg = (const float*)d_in[37];
  const float* bqg = (const float*)d_in[38];
  const float* wkg = (const float*)d_in[39];
  const float* bkg = (const float*)d_in[40];

  char* ws = (char*)d_ws;
  size_t off = 0;
  auto alloc = [&](size_t bytes) {
    size_t r = off;
    off += (bytes + 255) & ~(size_t)255;
    return r;
  };
  float* pos_h    = (float*)(ws + alloc((size_t)NF * MD * 4));
  float* pos      = (float*)(ws + alloc((size_t)NF * MD * 4));
  float* feat_pre = (float*)(ws + alloc((size_t)NF * MD * 4));
  float* feat     = (float*)(ws + alloc((size_t)NF * MD * 4));
  float* satf_pre = (float*)(ws + alloc((size_t)NS * MD * 4));
  float* satf     = (float*)(ws + alloc((size_t)NS * MD * 4));
  float* v_lin    = (float*)(ws + alloc((size_t)NS * MD * 4));
  float* plk_h    = (float*)(ws + alloc((size_t)NF * GHID * 4));
  float* plk2     = (float*)(ws + alloc((size_t)NF * GHID * 4));
  float* sxy_h    = (float*)(ws + alloc((size_t)NS * GHID * 4));
  float* sxy2     = (float*)(ws + alloc((size_t)NS * GHID * 4));
  u16* Qaug = (u16*)(ws + alloc((size_t)8 * NF * DA * 2));
  u16* Kaug = (u16*)(ws + alloc((size_t)8 * NS * DA * 2));
  u16* VT   = (u16*)(ws + alloc((size_t)8 * HD * NS * 2));
  // aliases (lifetimes verified, ~54 MB total workspace)
  float* q_embed = pos_h;     // pos_h dead after pos GEMM
  float* q_lin   = feat_pre;  // feat_pre dead after feat LN
  float* k_lin   = satf_pre;  // satf_pre dead after satf LN
  float* plk_ln  = plk_h;     // plk_h dead after plk2 GEMM
  float* qg_lin  = plk2;      // plk2 dead after plk_ln LN
  float* sgf_ln  = sxy_h;
  float* kg_lin  = sxy2;

  dim3 b256(256);
  // layer-1 small-K MLPs
  k_silu_lin<<<dim3((NF * MD + 255) / 256), b256, 0, stream>>>(bev_xy, pos_w1, pos_b1, pos_h, NF, MD, 2);
  k_silu_lin<<<dim3((NF * GHID + 255) / 256), b256, 0, stream>>>(plucker, plk_w1, plk_b1, plk_h, NF, GHID, 6);
  k_silu_lin<<<dim3((NS * GHID + 255) / 256), b256, 0, stream>>>(sat_xy, sxy_w1, sxy_b1, sxy_h, NS, GHID, 2);
  // projection GEMMs (bf16 MFMA)
  k_gemm<false><<<dim3(NF / 64, MD / 64), b256, 0, stream>>>(pos_h, pos_w2, pos, NF, MD, MD);
  k_gemm<true><<<dim3(NF / 64, MD / 64), b256, 0, stream>>>(front_feat, fa_w, feat_pre, NF, MD, 320);
  k_gemm<false><<<dim3(NS / 64, MD / 64), b256, 0, stream>>>(sat_tokens, sa_w, satf_pre, NS, MD, 768);
  k_gemm<false><<<dim3(NF / 64, GHID / 64), b256, 0, stream>>>(plk_h, plk_w2, plk2, NF, GHID, GHID);
  k_gemm<false><<<dim3(NS / 64, GHID / 64), b256, 0, stream>>>(sxy_h, sxy_w2, sxy2, NS, GHID, GHID);
  // LayerNorms
  k_ln<<<dim3(NF), b256, 0, stream>>>(feat_pre, fa_b, nullptr, fa_ln_g, fa_ln_b, feat, MD);
  k_ln<<<dim3(NS), b256, 0, stream>>>(satf_pre, sa_b, nullptr, sa_ln_g, sa_ln_b, satf, MD);
  k_ln<<<dim3(NF), b256, 0, stream>>>(pos, pos_b2, feat, qn_g, qn_b, q_embed, MD);
  k_ln<<<dim3(NF), b256, 0, stream>>>(plk2, plk_b2, nullptr, gqn_g, gqn_b, plk_ln, GHID);
  k_ln<<<dim3(NS), b256, 0, stream>>>(sxy2, sxy_b2, nullptr, gkn_g, gkn_b, sgf_ln, GHID);
  // q/k/v + geo projections
  k_gemm<false><<<dim3(NF / 64, MD / 64), b256, 0, stream>>>(q_embed, wq, q_lin, NF, MD, MD);
  k_gemm<false><<<dim3(NS / 64, MD / 64), b256, 0, stream>>>(satf, wk, k_lin, NS, MD, MD);
  k_gemm<false><<<dim3(NS / 64, MD / 64), b256, 0, stream>>>(satf, wv, v_lin, NS, MD, MD);
  k_gemm<false><<<dim3(NF / 64, GHID / 64), b256, 0, stream>>>(plk_ln, wqg, qg_lin, NF, GHID, GHID);
  k_gemm<false><<<dim3(NS / 64, GHID / 64), b256, 0, stream>>>(sgf_ln, wkg, kg_lin, NS, GHID, GHID);
  // augmented Q/K/V prep (bias + GeoRoPE + scale folding, cast bf16)
  k_qk_prep<<<dim3(NF * 8 / 4), b256, 0, stream>>>(q_lin, bq, qg_lin, bqg, bev_xy, Qaug, NF, 0.125f, 0.25f);
  k_qk_prep<<<dim3(NS * 8 / 4), b256, 0, stream>>>(k_lin, bk, kg_lin, bkg, sat_xy, Kaug, NS, 1.f, 1.f);
  k_v_prep<<<dim3(8 * HD * NS / 256), b256, 0, stream>>>(v_lin, bv, VT);
  // fused attention (dist2 in f32 inside)
  k_flash<<<dim3(NF / 64, 8), b256, 0, stream>>>(Qaug, Kaug, VT, bev_xy, sat_xy, (float*)d_out);
}

// Round 3
// 160.543 us; speedup vs baseline: 1.4540x; 1.4540x over previous
//
#include <hip/hip_runtime.h>
#include <hip/hip_bf16.h>
#include <stdint.h>

// Problem constants
#define NF 4096
#define NS 1024
#define MD 512
#define HD 64
#define DA 96
#define GHID 128

#define L2E 1.44269504f          // log2(e)
#define S2L 1.6986436f           // sqrt(2*log2e)  (LAMBDA_GEO=1)

typedef unsigned short u16;
typedef __attribute__((ext_vector_type(8))) short bf8v;   // 8 bf16
typedef __attribute__((ext_vector_type(4))) float f4v;

__device__ __forceinline__ u16 f2bf(float f) {
  __hip_bfloat16 h = __float2bfloat16(f);
  return __builtin_bit_cast(u16, h);
}
__device__ __forceinline__ float bf2f(u16 u) {
  union { unsigned u; float f; } v; v.u = ((unsigned)u) << 16; return v.f;
}
__device__ __forceinline__ f4v mfma16(bf8v a, bf8v b, f4v c) {
  return __builtin_amdgcn_mfma_f32_16x16x32_bf16(a, b, c, 0, 0, 0);
}
__device__ __forceinline__ void gld16(const void* g, void* l) {
  __builtin_amdgcn_global_load_lds(
      (const __attribute__((address_space(1))) unsigned int*)g,
      (__attribute__((address_space(3))) unsigned int*)l, 16, 0, 0);
}

// ---------------- mega convert: all weights + sat_tokens f32->bf16 pool, bkv build ----------------
#define OFF_POSW2 0
#define OFF_FAW   262144
#define OFF_SAW   425984
#define OFF_WQ    819200
#define OFF_WKV   1081344
#define OFF_PLKW2 1605632
#define OFF_SXYW2 1622016
#define OFF_WQG   1638400
#define OFF_WKG   1654784
#define OFF_SATT  1671168
#define TOTW      2457600

__global__ void k_convert(const float* __restrict__ s0, const float* __restrict__ s1,
                          const float* __restrict__ s2, const float* __restrict__ s3,
                          const float* __restrict__ s4, const float* __restrict__ s5,
                          const float* __restrict__ s6, const float* __restrict__ s7,
                          const float* __restrict__ s8, const float* __restrict__ s9,
                          const float* __restrict__ s10, u16* __restrict__ pool,
                          const float* __restrict__ bk, const float* __restrict__ bv,
                          float* __restrict__ bkv) {
  int i4 = blockIdx.x * 256 + threadIdx.x;
  if (i4 < TOTW / 4) {
    int idx = i4 * 4;
    const float* src; int off;
    if      (idx < OFF_FAW)   { src = s0;  off = OFF_POSW2; }
    else if (idx < OFF_SAW)   { src = s1;  off = OFF_FAW; }
    else if (idx < OFF_WQ)    { src = s2;  off = OFF_SAW; }
    else if (idx < OFF_WKV)   { src = s3;  off = OFF_WQ; }
    else if (idx < 1343488)   { src = s4;  off = OFF_WKV; }
    else if (idx < OFF_PLKW2) { src = s5;  off = 1343488; }
    else if (idx < OFF_SXYW2) { src = s6;  off = OFF_PLKW2; }
    else if (idx < OFF_WQG)   { src = s7;  off = OFF_SXYW2; }
    else if (idx < OFF_WKG)   { src = s8;  off = OFF_WQG; }
    else if (idx < OFF_SATT)  { src = s9;  off = OFF_WKG; }
    else                      { src = s10; off = OFF_SATT; }
    float4 v = *(const float4*)(src + (idx - off));
    ushort4 o;
    o.x = f2bf(v.x); o.y = f2bf(v.y); o.z = f2bf(v.z); o.w = f2bf(v.w);
    *(ushort4*)(pool + idx) = o;
  } else if (i4 < TOTW / 4 + 256) {
    int j = (i4 - TOTW / 4) * 4;
#pragma unroll
    for (int e = 0; e < 4; ++e) {
      int b = j + e;
      bkv[b] = (b < 512) ? bk[b] : bv[b - 512];
    }
  }
}

// ---------------- front_feat transpose+convert: f32 [320][4096] -> bf16 [4096][320] ----------------
__global__ void k_ffT(const float* __restrict__ ff, u16* __restrict__ out) {
  __shared__ u16 sT[32][72];
  int n0 = blockIdx.x * 64, c0 = blockIdx.y * 32;
  int t = threadIdx.x;
  {
    int cr = t >> 3, nc = (t & 7) * 8;   // cr in [0,32), nc in [0,64)
    const float* src = ff + (size_t)(c0 + cr) * NF + n0 + nc;
    float4 v0 = *(const float4*)src, v1 = *(const float4*)(src + 4);
    bf8v p;
    p[0]=(short)f2bf(v0.x); p[1]=(short)f2bf(v0.y); p[2]=(short)f2bf(v0.z); p[3]=(short)f2bf(v0.w);
    p[4]=(short)f2bf(v1.x); p[5]=(short)f2bf(v1.y); p[6]=(short)f2bf(v1.z); p[7]=(short)f2bf(v1.w);
    *(bf8v*)&sT[cr][nc] = p;
  }
  __syncthreads();
  {
    int r = t >> 2, cc = (t & 3) * 8;    // r in [0,64), cc in [0,32)
    bf8v p;
#pragma unroll
    for (int e = 0; e < 8; ++e) p[e] = (short)sT[cc + e][r];
    *(bf8v*)(out + (size_t)(n0 + r) * 320 + c0 + cc) = p;
  }
}

// ---------------- V transpose: kv_lin[:,512+h*64+d] -> VT[h][d][n] (bf16 copy) ----------------
__global__ void k_vt(const u16* __restrict__ kv, u16* __restrict__ VT) {
  __shared__ u16 sT[64][72];
  int n0 = blockIdx.x * 64, h = blockIdx.y;
  int t = threadIdx.x;
  int r = t >> 2, c = (t & 3) * 16;
  const u16* src = kv + (size_t)(n0 + r) * 1024 + 512 + h * 64 + c;
  *(bf8v*)&sT[r][c]     = *(const bf8v*)src;
  *(bf8v*)&sT[r][c + 8] = *(const bf8v*)(src + 8);
  __syncthreads();
  int d = t >> 2, nc = (t & 3) * 16;
  bf8v p0, p1;
#pragma unroll
  for (int e = 0; e < 8; ++e) { p0[e] = (short)sT[nc + e][d]; p1[e] = (short)sT[nc + 8 + e][d]; }
  u16* dst = VT + (size_t)(h * 64 + d) * 1024 + n0 + nc;
  *(bf8v*)dst = p0;
  *(bf8v*)(dst + 8) = p1;
}

// ---------------- small-K silu MLP: out = bf16(silu(in @ w^T + b)) ----------------
__global__ void k_silu(const float* __restrict__ in, const float* __restrict__ w,
                       const float* __restrict__ b, u16* __restrict__ out,
                       int N, int mlog, int K) {
  int idx = blockIdx.x * 256 + threadIdx.x;
  int M = 1 << mlog;
  if (idx >= N * M) return;
  int n = idx >> mlog, m = idx & (M - 1);
  float acc = b[m];
  for (int k = 0; k < K; ++k) acc += in[n * K + k] * w[m * K + k];
  out[idx] = f2bf(acc / (1.f + __expf(-acc)));
}

// ---------------- LayerNorm (bf16 in/out, wave per row) ----------------
template <int D>
__global__ void k_ln_bf(const u16* __restrict__ in1, const u16* __restrict__ in2,
                        const float* __restrict__ g, const float* __restrict__ beta,
                        u16* __restrict__ out) {
  constexpr int E = D / 64;
  int w = threadIdx.x >> 6, lane = threadIdx.x & 63;
  int row = blockIdx.x * 4 + w;
  const u16* p1 = in1 + (size_t)row * D + lane * E;
  float x[E];
  if constexpr (E == 8) {
    bf8v v = *(const bf8v*)p1;
#pragma unroll
    for (int e = 0; e < 8; ++e) x[e] = bf2f((u16)v[e]);
    if (in2) {
      bf8v v2 = *(const bf8v*)(in2 + (size_t)row * D + lane * E);
#pragma unroll
      for (int e = 0; e < 8; ++e) x[e] += bf2f((u16)v2[e]);
    }
  } else {
    uint32_t v = *(const uint32_t*)p1;
    x[0] = bf2f((u16)(v & 0xffff)); x[1] = bf2f((u16)(v >> 16));
    if (in2) {
      uint32_t v2 = *(const uint32_t*)(in2 + (size_t)row * D + lane * E);
      x[0] += bf2f((u16)(v2 & 0xffff)); x[1] += bf2f((u16)(v2 >> 16));
    }
  }
  float s = 0.f, q = 0.f;
#pragma unroll
  for (int e = 0; e < E; ++e) { s += x[e]; q += x[e] * x[e]; }
#pragma unroll
  for (int mm = 1; mm < 64; mm <<= 1) { s += __shfl_xor(s, mm); q += __shfl_xor(q, mm); }
  float mean = s / D, var = q / D - mean * mean;
  float rstd = rsqrtf(var + 1e-5f);
  u16 o[E];
#pragma unroll
  for (int e = 0; e < E; ++e)
    o[e] = f2bf((x[e] - mean) * rstd * g[lane * E + e] + beta[lane * E + e]);
  if constexpr (E == 8) {
    bf8v ov;
#pragma unroll
    for (int e = 0; e < 8; ++e) ov[e] = (short)o[e];
    *(bf8v*)(out + (size_t)row * D + lane * E) = ov;
  } else {
    *(uint32_t*)(out + (size_t)row * D + lane * E) = (uint32_t)o[0] | ((uint32_t)o[1] << 16);
  }
}

// ---------------- bf16 MFMA GEMM, BK=64, dbuf LDS, global_load_lds + XOR swizzle ----------------
// A [M][K] bf16, W [N][K] bf16, bias f32 [N] (nullable), out [M][N] bf16. M%BM==0, N%BN==0, K%64==0.
template <int BM, int BN>
__global__ __launch_bounds__(256) void k_gemm_bf(const u16* __restrict__ A,
                                                 const u16* __restrict__ W,
                                                 const float* __restrict__ bias,
                                                 u16* __restrict__ out,
                                                 int M, int N, int K) {
  constexpr int WTM = BM / 2, WTN = BN / 2;
  constexpr int MR = WTM / 16, NR = WTN / 16;
  __shared__ u16 sA[2][BM * 64];
  __shared__ u16 sB[2][BN * 64];
  const int m0 = blockIdx.x * BM, n0 = blockIdx.y * BN;
  const int tid = threadIdx.x, w = tid >> 6, lane = tid & 63;
  const int l16 = lane & 15, lh = lane >> 4;
  const int wr = w >> 1, wc = w & 1;

  f4v acc[MR][NR];
#pragma unroll
  for (int m = 0; m < MR; ++m)
#pragma unroll
    for (int j = 0; j < NR; ++j) acc[m][j] = (f4v){0.f, 0.f, 0.f, 0.f};

  auto stageA = [&](int buf, int k0) {
#pragma unroll
    for (int i = 0; i < BM * 8 / 256; ++i) {
      int c = i * 256 + tid;
      int row = c >> 3, cp = c & 7;
      int sc_ = cp ^ (row & 7);
      gld16(A + (size_t)(m0 + row) * K + k0 + sc_ * 8, &sA[buf][c * 8]);
    }
  };
  auto stageB = [&](int buf, int k0) {
#pragma unroll
    for (int i = 0; i < BN * 8 / 256; ++i) {
      int c = i * 256 + tid;
      int row = c >> 3, cp = c & 7;
      int sc_ = cp ^ (row & 7);
      gld16(W + (size_t)(n0 + row) * K + k0 + sc_ * 8, &sB[buf][c * 8]);
    }
  };

  stageA(0, 0); stageB(0, 0);
  __syncthreads();
  const int NK = K >> 6;
  for (int ks = 0; ks < NK; ++ks) {
    int nb = ks & 1;
    if (ks + 1 < NK) { stageA(nb ^ 1, (ks + 1) * 64); stageB(nb ^ 1, (ks + 1) * 64); }
#pragma unroll
    for (int kk = 0; kk < 2; ++kk) {
      bf8v af[MR], bfr[NR];
#pragma unroll
      for (int m = 0; m < MR; ++m) {
        int row = wr * WTM + m * 16 + l16;
        int cp = (kk * 4 + lh) ^ (row & 7);
        af[m] = *(const bf8v*)&sA[nb][row * 64 + cp * 8];
      }
#pragma unroll
      for (int j = 0; j < NR; ++j) {
        int row = wc * WTN + j * 16 + l16;
        int cp = (kk * 4 + lh) ^ (row & 7);
        bfr[j] = *(const bf8v*)&sB[nb][row * 64 + cp * 8];
      }
#pragma unroll
      for (int m = 0; m < MR; ++m)
#pragma unroll
        for (int j = 0; j < NR; ++j) acc[m][j] = mfma16(af[m], bfr[j], acc[m][j]);
    }
    __syncthreads();
  }
#pragma unroll
  for (int m = 0; m < MR; ++m) {
    int grow = m0 + wr * WTM + m * 16 + (lh << 2);
#pragma unroll
    for (int j = 0; j < NR; ++j) {
      int gcol = n0 + wc * WTN + j * 16 + l16;
      float bv = bias ? bias[gcol] : 0.f;
#pragma unroll
      for (int r = 0; r < 4; ++r)
        out[(size_t)(grow + r) * N + gcol] = f2bf(acc[m][j][r] + bv);
    }
  }
}

// ---------------- augmented Q/K prep (rope + geo head + xy cross dims, bf16) ----------------
__global__ void k_qk_prep(const u16* __restrict__ lin, int lstride,
                          const u16* __restrict__ glin, int gstride,
                          const float* __restrict__ xy, u16* __restrict__ aug,
                          float* __restrict__ kk2,   // null for Q side
                          int N, float scm, float scg, int isQ) {
  int gid = blockIdx.x * 4 + (threadIdx.x >> 6);
  int lane = threadIdx.x & 63;
  int n = gid >> 3, h = gid & 7;
  if (n >= N) return;
  float val = bf2f(lin[(size_t)n * lstride + h * 64 + lane]);
  float part = __shfl_xor(val, 8);
  float x = xy[n * 2], y = xy[n * 2 + 1];
  float outv = val;
  if (lane < 32) {
    float coord = (lane < 16) ? x : y;
    int j = lane & 7;
    float th = coord * __expf(-(float)j * 1.1512925465f);   // 10000^(-j/8)
    float sn, cs;
    __sincosf(th, &sn, &cs);
    outv = ((lane & 8) == 0) ? (val * cs - part * sn) : (part * sn + val * cs);
  }
  u16* dst = aug + (size_t)(h * N + n) * DA;
  dst[lane] = f2bf(outv * scm);
  if (lane < 16) {
    float gv = bf2f(glin[(size_t)n * gstride + h * 16 + lane]);
    dst[64 + lane] = f2bf(gv * scg);
  } else if (lane == 16) {
    dst[80] = f2bf(S2L * x);
  } else if (lane == 17) {
    dst[81] = f2bf(S2L * y);
  } else if (lane == 18) {
    dst[82] = 0;
    if (!isQ && h == 0 && kk2) kk2[n] = L2E * (x * x + y * y);
  } else if (lane < 32) {
    dst[64 + lane] = 0;
  }
}

// ---------------- fused flash attention, NS split by 2, exp2-domain softmax ----------------
__global__ __launch_bounds__(256, 4) void k_flash(const u16* __restrict__ Qa,
                                                  const u16* __restrict__ Ka,
                                                  const u16* __restrict__ VT,
                                                  const float* __restrict__ kk2,
                                                  float* __restrict__ Opart,
                                                  float2* __restrict__ ml) {
  const int h = blockIdx.y, qb = blockIdx.x, sp = blockIdx.z;
  const int tid = threadIdx.x, w = tid >> 6, lane = tid & 63;
  const int l16 = lane & 15, lh = lane >> 4;
  __shared__ u16 sK[2][64][104];
  __shared__ u16 sV[2][64][72];
  __shared__ u16 sP[4][16][72];

  const int qrow = qb * 64 + w * 16 + l16;
  bf8v qf[3];
#pragma unroll
  for (int c = 0; c < 3; ++c)
    qf[c] = *(const bf8v*)(Qa + (size_t)(h * NF + qrow) * DA + c * 32 + lh * 8);

  bf8v ONES;
#pragma unroll
  for (int i = 0; i < 8; ++i) ONES[i] = (short)0x3F80;

  const int crow = qb * 64 + w * 16 + (lh << 2);
  float m_run[4], l_run[4];
  f4v accO[4];
#pragma unroll
  for (int r = 0; r < 4; ++r) { m_run[r] = -1e30f; l_run[r] = 0.f; }
#pragma unroll
  for (int d = 0; d < 4; ++d) accO[d] = (f4v){0.f, 0.f, 0.f, 0.f};

  const int kt0 = sp * 8;
  bf8v kreg[3], vreg[2];
  auto sload = [&](int t8) {
    int kb = (kt0 + t8) * 64;
#pragma unroll
    for (int i = 0; i < 3; ++i) {
      int c = tid + i * 256; int r = c / 12, off = (c % 12) * 8;
      kreg[i] = *(const bf8v*)(Ka + ((size_t)(h * NS) + kb + r) * DA + off);
    }
#pragma unroll
    for (int i = 0; i < 2; ++i) {
      int c = tid + i * 256; int d = c >> 3, off = (c & 7) * 8;
      vreg[i] = *(const bf8v*)(VT + ((size_t)(h * HD) + d) * NS + kb + off);
    }
  };
  auto swrite = [&](int b) {
#pragma unroll
    for (int i = 0; i < 3; ++i) {
      int c = tid + i * 256; int r = c / 12, off = (c % 12) * 8;
      *(bf8v*)&sK[b][r][off] = kreg[i];
    }
#pragma unroll
    for (int i = 0; i < 2; ++i) {
      int c = tid + i * 256; int d = c >> 3, off = (c & 7) * 8;
      *(bf8v*)&sV[b][d][off] = vreg[i];
    }
  };

  sload(0); swrite(0);
  __syncthreads();
  int cur = 0;
  for (int t8 = 0; t8 < 8; ++t8) {
    if (t8 < 7) sload(t8 + 1);
    const int kb = (kt0 + t8) * 64;
    // ---- S = Qaug.Kaug - L2E*kk2  (exp2 domain) ----
    float p[4][4];
    float rmax[4] = {-1e30f, -1e30f, -1e30f, -1e30f};
#pragma unroll
    for (int j = 0; j < 4; ++j) {
      f4v s4 = (f4v){0.f, 0.f, 0.f, 0.f};
#pragma unroll
      for (int c = 0; c < 3; ++c) {
        bf8v kf = *(const bf8v*)&sK[cur][j * 16 + l16][c * 32 + lh * 8];
        s4 = mfma16(qf[c], kf, s4);
      }
      float ck = kk2[kb + j * 16 + l16];
#pragma unroll
      for (int r = 0; r < 4; ++r) {
        float sv = s4[r] - ck;
        p[j][r] = sv;
        rmax[r] = fmaxf(rmax[r], sv);
      }
    }
    // f32 max reduce over the 16-lane col group
#pragma unroll
    for (int r = 0; r < 4; ++r)
#pragma unroll
      for (int mm = 1; mm < 16; mm <<= 1)
        rmax[r] = fmaxf(rmax[r], __shfl_xor(rmax[r], mm));
    float sc[4];
#pragma unroll
    for (int r = 0; r < 4; ++r) {
      float mnew = fmaxf(m_run[r], rmax[r]);
      sc[r] = exp2f(m_run[r] - mnew);
      m_run[r] = mnew;
    }
#pragma unroll
    for (int j = 0; j < 4; ++j)
#pragma unroll
      for (int r = 0; r < 4; ++r) {
        p[j][r] = exp2f(p[j][r] - m_run[r]);
        sP[w][(lh << 2) + r][j * 16 + l16] = f2bf(p[j][r]);
      }
    bf8v pf0 = *(const bf8v*)&sP[w][l16][lh * 8];
    bf8v pf1 = *(const bf8v*)&sP[w][l16][32 + lh * 8];
    f4v ls = (f4v){0.f, 0.f, 0.f, 0.f};
    ls = mfma16(pf0, ONES, ls);
    ls = mfma16(pf1, ONES, ls);
#pragma unroll
    for (int r = 0; r < 4; ++r) {
      l_run[r] = l_run[r] * sc[r] + ls[r];
#pragma unroll
      for (int d = 0; d < 4; ++d) accO[d][r] *= sc[r];
    }
#pragma unroll
    for (int c = 0; c < 2; ++c) {
      bf8v pf = (c == 0) ? pf0 : pf1;
#pragma unroll
      for (int d = 0; d < 4; ++d) {
        bf8v vf = *(const bf8v*)&sV[cur][d * 16 + l16][c * 32 + lh * 8];
        accO[d] = mfma16(pf, vf, accO[d]);
      }
    }
    // ---- end compute ----
    if (t8 < 7) swrite(cur ^ 1);
    __syncthreads();
    cur ^= 1;
  }
  size_t obase = (size_t)(sp * 8 + h) * NF + crow;
#pragma unroll
  for (int d = 0; d < 4; ++d)
#pragma unroll
    for (int r = 0; r < 4; ++r)
      Opart[(obase + r) * 64 + d * 16 + l16] = accO[d][r];
  if (l16 == 0) {
#pragma unroll
    for (int r = 0; r < 4; ++r) ml[obase + r] = make_float2(m_run[r], l_run[r]);
  }
}

// ---------------- combine the 2 NS-splits ----------------
__global__ void k_combine(const float* __restrict__ Opart, const float2* __restrict__ ml,
                          float* __restrict__ out) {
  int i = blockIdx.x * 256 + threadIdx.x;   // 4096*512
  int n = i >> 9, c = i & 511, h = c >> 6, d = c & 63;
  float2 a = ml[(size_t)h * NF + n];
  float2 b = ml[(size_t)(8 + h) * NF + n];
  float m = fmaxf(a.x, b.x);
  float w1 = exp2f(a.x - m), w2 = exp2f(b.x - m);
  float l = a.y * w1 + b.y * w2;
  float o = Opart[((size_t)h * NF + n) * 64 + d] * w1 +
            Opart[((size_t)(8 + h) * NF + n) * 64 + d] * w2;
  out[i] = o / l;
}

extern "C" void kernel_launch(void* const* d_in, const int* in_sizes, int n_in,
                              void* d_out, int out_size, void* d_ws, size_t ws_size,
                              hipStream_t stream) {
  (void)in_sizes; (void)n_in; (void)out_size; (void)ws_size;
  const float* front_feat = (const float*)d_in[0];
  const float* bev_xy     = (const float*)d_in[1];
  const float* sat_tokens = (const float*)d_in[2];
  const float* sat_xy     = (const float*)d_in[3];
  const float* plucker    = (const float*)d_in[4];
  const float* pos_w1 = (const float*)d_in[5];
  const float* pos_b1 = (const float*)d_in[6];
  const float* pos_w2 = (const float*)d_in[7];
  const float* pos_b2 = (const float*)d_in[8];
  const float* fa_w   = (const float*)d_in[9];
  const float* fa_b   = (const float*)d_in[10];
  const float* fa_ln_g = (const float*)d_in[11];
  const float* fa_ln_b = (const float*)d_in[12];
  const float* qn_g   = (const float*)d_in[13];
  const float* qn_b   = (const float*)d_in[14];
  const float* sa_w   = (const float*)d_in[15];
  const float* sa_b   = (const float*)d_in[16];
  const float* sa_ln_g = (const float*)d_in[17];
  const float* sa_ln_b = (const float*)d_in[18];
  const float* wq = (const float*)d_in[19];
  const float* bq = (const float*)d_in[20];
  const float* wk = (const float*)d_in[21];
  const float* bk = (const float*)d_in[22];
  const float* wv = (const float*)d_in[23];
  const float* bv = (const float*)d_in[24];
  const float* plk_w1 = (const float*)d_in[25];
  const float* plk_b1 = (const float*)d_in[26];
  const float* plk_w2 = (const float*)d_in[27];
  const float* plk_b2 = (const float*)d_in[28];
  const float* sxy_w1 = (const float*)d_in[29];
  const float* sxy_b1 = (const float*)d_in[30];
  const float* sxy_w2 = (const float*)d_in[31];
  const float* sxy_b2 = (const float*)d_in[32];
  const float* gqn_g = (const float*)d_in[33];
  const float* gqn_b = (const float*)d_in[34];
  const float* gkn_g = (const float*)d_in[35];
  const float* gkn_b = (const float*)d_in[36];
  const float* wqg = (const float*)d_in[37];
  const float* bqg = (const float*)d_in[38];
  const float* wkg = (const float*)d_in[39];
  const float* bkg = (const float*)d_in[40];

  char* ws = (char*)d_ws;
  size_t off = 0;
  auto alloc = [&](size_t bytes) {
    size_t r = off;
    off += (bytes + 255) & ~(size_t)255;
    return r;
  };
  u16*   wpool   = (u16*)(ws + alloc((size_t)TOTW * 2));
  float* bkv     = (float*)(ws + alloc(1024 * 4));
  u16*   ffT     = (u16*)(ws + alloc((size_t)NF * 320 * 2));
  u16*   pos_h   = (u16*)(ws + alloc((size_t)NF * MD * 2));
  u16*   plk_h   = (u16*)(ws + alloc((size_t)NF * GHID * 2));
  u16*   sxy_h   = (u16*)(ws + alloc((size_t)NS * GHID * 2));
  u16*   pos     = (u16*)(ws + alloc((size_t)NF * MD * 2));
  u16*   feat_pre= (u16*)(ws + alloc((size_t)NF * MD * 2));
  u16*   satf_pre= (u16*)(ws + alloc((size_t)NS * MD * 2));
  u16*   feat    = (u16*)(ws + alloc((size_t)NF * MD * 2));
  u16*   satf    = (u16*)(ws + alloc((size_t)NS * MD * 2));
  u16*   q_embed = (u16*)(ws + alloc((size_t)NF * MD * 2));
  u16*   plk2    = (u16*)(ws + alloc((size_t)NF * GHID * 2));
  u16*   sxy2    = (u16*)(ws + alloc((size_t)NS * GHID * 2));
  u16*   q_lin   = (u16*)(ws + alloc((size_t)NF * MD * 2));
  u16*   kv_lin  = (u16*)(ws + alloc((size_t)NS * 1024 * 2));
  u16*   Qaug    = (u16*)(ws + alloc((size_t)8 * NF * DA * 2));
  u16*   Kaug    = (u16*)(ws + alloc((size_t)8 * NS * DA * 2));
  u16*   VT      = (u16*)(ws + alloc((size_t)8 * HD * NS * 2));
  float* kk2     = (float*)(ws + alloc((size_t)NS * 4));
  float* Opart   = (float*)(ws + alloc((size_t)2 * 8 * NF * 64 * 4));
  float2* mlb    = (float2*)(ws + alloc((size_t)2 * 8 * NF * 8));
  // aliases (producer dead before alias written)
  u16* plk_ln = plk_h;    // plk_h dead after plk2 GEMM
  u16* sgf    = sxy_h;
  u16* qg_lin = plk2;     // plk2 dead after plk_ln LN
  u16* kg_lin = sxy2;

  dim3 b256(256);
  k_convert<<<dim3(TOTW / 4 / 256 + 1), b256, 0, stream>>>(
      pos_w2, fa_w, sa_w, wq, wk, wv, plk_w2, sxy_w2, wqg, wkg, sat_tokens,
      wpool, bk, bv, bkv);
  k_ffT<<<dim3(64, 10), b256, 0, stream>>>(front_feat, ffT);
  k_silu<<<dim3(NF * MD / 256), b256, 0, stream>>>(bev_xy, pos_w1, pos_b1, pos_h, NF, 9, 2);
  k_silu<<<dim3(NF * GHID / 256), b256, 0, stream>>>(plucker, plk_w1, plk_b1, plk_h, NF, 7, 6);
  k_silu<<<dim3(NS * GHID / 256), b256, 0, stream>>>(sat_xy, sxy_w1, sxy_b1, sxy_h, NS, 7, 2);

  k_gemm_bf<128, 64><<<dim3(NF / 128, MD / 64), b256, 0, stream>>>(pos_h, wpool + OFF_POSW2, pos_b2, pos, NF, MD, MD);
  k_gemm_bf<128, 64><<<dim3(NF / 128, MD / 64), b256, 0, stream>>>(ffT, wpool + OFF_FAW, fa_b, feat_pre, NF, MD, 320);
  k_gemm_bf<64, 64><<<dim3(NS / 64, MD / 64), b256, 0, stream>>>(wpool + OFF_SATT, wpool + OFF_SAW, sa_b, satf_pre, NS, MD, 768);
  k_gemm_bf<64, 64><<<dim3(NF / 64, GHID / 64), b256, 0, stream>>>(plk_h, wpool + OFF_PLKW2, plk_b2, plk2, NF, GHID, GHID);
  k_gemm_bf<64, 64><<<dim3(NS / 64, GHID / 64), b256, 0, stream>>>(sxy_h, wpool + OFF_SXYW2, sxy_b2, sxy2, NS, GHID, GHID);

  k_ln_bf<512><<<dim3(NF / 4), b256, 0, stream>>>(feat_pre, nullptr, fa_ln_g, fa_ln_b, feat);
  k_ln_bf<512><<<dim3(NS / 4), b256, 0, stream>>>(satf_pre, nullptr, sa_ln_g, sa_ln_b, satf);
  k_ln_bf<512><<<dim3(NF / 4), b256, 0, stream>>>(pos, feat, qn_g, qn_b, q_embed);
  k_ln_bf<128><<<dim3(NF / 4), b256, 0, stream>>>(plk2, nullptr, gqn_g, gqn_b, plk_ln);
  k_ln_bf<128><<<dim3(NS / 4), b256, 0, stream>>>(sxy2, nullptr, gkn_g, gkn_b, sgf);

  k_gemm_bf<128, 64><<<dim3(NF / 128, MD / 64), b256, 0, stream>>>(q_embed, wpool + OFF_WQ, bq, q_lin, NF, MD, MD);
  k_gemm_bf<64, 64><<<dim3(NS / 64, 1024 / 64), b256, 0, stream>>>(satf, wpool + OFF_WKV, bkv, kv_lin, NS, 1024, MD);
  k_gemm_bf<64, 64><<<dim3(NF / 64, GHID / 64), b256, 0, stream>>>(plk_ln, wpool + OFF_WQG, bqg, qg_lin, NF, GHID, GHID);
  k_gemm_bf<64, 64><<<dim3(NS / 64, GHID / 64), b256, 0, stream>>>(sgf, wpool + OFF_WKG, bkg, kg_lin, NS, GHID, GHID);

  k_qk_prep<<<dim3(NF * 8 / 4), b256, 0, stream>>>(q_lin, MD, qg_lin, GHID, bev_xy, Qaug, nullptr,
                                                   NF, 0.125f * L2E, 0.25f * L2E, 1);
  k_qk_prep<<<dim3(NS * 8 / 4), b256, 0, stream>>>(kv_lin, 1024, kg_lin, GHID, sat_xy, Kaug, kk2,
                                                   NS, 1.f, 1.f, 0);
  k_vt<<<dim3(NS / 64, 8), b256, 0, stream>>>(kv_lin, VT);

  k_flash<<<dim3(NF / 64, 8, 2), b256, 0, stream>>>(Qaug, Kaug, VT, kk2, Opart, mlb);
  k_combine<<<dim3(NF * MD / 256), b256, 0, stream>>>(Opart, mlb, (float*)d_out);
}

// Round 4
// 124.801 us; speedup vs baseline: 1.8704x; 1.2864x over previous
//
#include <hip/hip_runtime.h>
#include <hip/hip_bf16.h>
#include <stdint.h>

// Problem constants
#define NF 4096
#define NS 1024
#define MD 512
#define HD 64
#define DA 96
#define GHID 128

#define L2E 1.44269504f          // log2(e)
#define S2L 1.6986436f           // sqrt(2*log2e)  (LAMBDA_GEO=1)

typedef unsigned short u16;
typedef __attribute__((ext_vector_type(8))) short bf8v;   // 8 bf16
typedef __attribute__((ext_vector_type(4))) float f4v;

__device__ __forceinline__ u16 f2bf(float f) {
  __hip_bfloat16 h = __float2bfloat16(f);
  return __builtin_bit_cast(u16, h);
}
__device__ __forceinline__ float bf2f(u16 u) {
  union { unsigned u; float f; } v; v.u = ((unsigned)u) << 16; return v.f;
}
__device__ __forceinline__ f4v mfma16(bf8v a, bf8v b, f4v c) {
  return __builtin_amdgcn_mfma_f32_16x16x32_bf16(a, b, c, 0, 0, 0);
}
__device__ __forceinline__ void gld16(const void* g, void* l) {
  __builtin_amdgcn_global_load_lds(
      (const __attribute__((address_space(1))) unsigned int*)g,
      (__attribute__((address_space(3))) unsigned int*)l, 16, 0, 0);
}

// ---------------- mega convert: all weights + sat_tokens f32->bf16 pool, bkv build ----------------
#define OFF_POSW2 0
#define OFF_FAW   262144
#define OFF_SAW   425984
#define OFF_WQ    819200
#define OFF_WKV   1081344
#define OFF_PLKW2 1605632
#define OFF_SXYW2 1622016
#define OFF_WQG   1638400
#define OFF_WKG   1654784
#define OFF_SATT  1671168
#define TOTW      2457600

__global__ void k_convert(const float* __restrict__ s0, const float* __restrict__ s1,
                          const float* __restrict__ s2, const float* __restrict__ s3,
                          const float* __restrict__ s4, const float* __restrict__ s5,
                          const float* __restrict__ s6, const float* __restrict__ s7,
                          const float* __restrict__ s8, const float* __restrict__ s9,
                          const float* __restrict__ s10, u16* __restrict__ pool,
                          const float* __restrict__ bk, const float* __restrict__ bv,
                          float* __restrict__ bkv) {
  int i4 = blockIdx.x * 256 + threadIdx.x;
  if (i4 < TOTW / 4) {
    int idx = i4 * 4;
    const float* src; int off;
    if      (idx < OFF_FAW)   { src = s0;  off = OFF_POSW2; }
    else if (idx < OFF_SAW)   { src = s1;  off = OFF_FAW; }
    else if (idx < OFF_WQ)    { src = s2;  off = OFF_SAW; }
    else if (idx < OFF_WKV)   { src = s3;  off = OFF_WQ; }
    else if (idx < 1343488)   { src = s4;  off = OFF_WKV; }
    else if (idx < OFF_PLKW2) { src = s5;  off = 1343488; }
    else if (idx < OFF_SXYW2) { src = s6;  off = OFF_PLKW2; }
    else if (idx < OFF_WQG)   { src = s7;  off = OFF_SXYW2; }
    else if (idx < OFF_WKG)   { src = s8;  off = OFF_WQG; }
    else if (idx < OFF_SATT)  { src = s9;  off = OFF_WKG; }
    else                      { src = s10; off = OFF_SATT; }
    float4 v = *(const float4*)(src + (idx - off));
    ushort4 o;
    o.x = f2bf(v.x); o.y = f2bf(v.y); o.z = f2bf(v.z); o.w = f2bf(v.w);
    *(ushort4*)(pool + idx) = o;
  } else if (i4 < TOTW / 4 + 256) {
    int j = (i4 - TOTW / 4) * 4;
#pragma unroll
    for (int e = 0; e < 4; ++e) {
      int b = j + e;
      bkv[b] = (b < 512) ? bk[b] : bv[b - 512];
    }
  }
}

// ---------------- front_feat transpose+convert: f32 [320][4096] -> bf16 [4096][320] ----------------
__global__ void k_ffT(const float* __restrict__ ff, u16* __restrict__ out) {
  __shared__ u16 sT[32][72];
  int n0 = blockIdx.x * 64, c0 = blockIdx.y * 32;
  int t = threadIdx.x;
  {
    int cr = t >> 3, nc = (t & 7) * 8;
    const float* src = ff + (size_t)(c0 + cr) * NF + n0 + nc;
    float4 v0 = *(const float4*)src, v1 = *(const float4*)(src + 4);
    bf8v p;
    p[0]=(short)f2bf(v0.x); p[1]=(short)f2bf(v0.y); p[2]=(short)f2bf(v0.z); p[3]=(short)f2bf(v0.w);
    p[4]=(short)f2bf(v1.x); p[5]=(short)f2bf(v1.y); p[6]=(short)f2bf(v1.z); p[7]=(short)f2bf(v1.w);
    *(bf8v*)&sT[cr][nc] = p;
  }
  __syncthreads();
  {
    int r = t >> 2, cc = (t & 3) * 8;
    bf8v p;
#pragma unroll
    for (int e = 0; e < 8; ++e) p[e] = (short)sT[cc + e][r];
    *(bf8v*)(out + (size_t)(n0 + r) * 320 + c0 + cc) = p;
  }
}

// ---------------- V transpose: kv_lin[:,512+h*64+d] -> VT[h][d][n] ----------------
__global__ void k_vt(const u16* __restrict__ kv, u16* __restrict__ VT) {
  __shared__ u16 sT[64][72];
  int n0 = blockIdx.x * 64, h = blockIdx.y;
  int t = threadIdx.x;
  int r = t >> 2, c = (t & 3) * 16;
  const u16* src = kv + (size_t)(n0 + r) * 1024 + 512 + h * 64 + c;
  *(bf8v*)&sT[r][c]     = *(const bf8v*)src;
  *(bf8v*)&sT[r][c + 8] = *(const bf8v*)(src + 8);
  __syncthreads();
  int d = t >> 2, nc = (t & 3) * 16;
  bf8v p0, p1;
#pragma unroll
  for (int e = 0; e < 8; ++e) { p0[e] = (short)sT[nc + e][d]; p1[e] = (short)sT[nc + 8 + e][d]; }
  u16* dst = VT + (size_t)(h * 64 + d) * 1024 + n0 + nc;
  *(bf8v*)dst = p0;
  *(bf8v*)(dst + 8) = p1;
}

// ---------------- fused small-K silu MLPs (pos_h, plk_h, sxy_h in one launch) ----------------
__global__ void k_siluF(const float* __restrict__ in0, const float* __restrict__ w0,
                        const float* __restrict__ b0, u16* __restrict__ o0,
                        const float* __restrict__ in1, const float* __restrict__ w1,
                        const float* __restrict__ b1, u16* __restrict__ o1,
                        const float* __restrict__ in2, const float* __restrict__ w2,
                        const float* __restrict__ b2, u16* __restrict__ o2) {
  int blk = blockIdx.x;
  const float *in, *w, *b; u16* o; int mlog, K, idx;
  if (blk < 8192)       { in = in0; w = w0; b = b0; o = o0; mlog = 9; K = 2; idx = blk * 256 + threadIdx.x; }
  else if (blk < 10240) { in = in1; w = w1; b = b1; o = o1; mlog = 7; K = 6; idx = (blk - 8192) * 256 + threadIdx.x; }
  else                  { in = in2; w = w2; b = b2; o = o2; mlog = 7; K = 2; idx = (blk - 10240) * 256 + threadIdx.x; }
  int M = 1 << mlog;
  int n = idx >> mlog, m = idx & (M - 1);
  float acc = b[m];
  for (int k = 0; k < K; ++k) acc += in[n * K + k] * w[m * K + k];
  o[idx] = f2bf(acc / (1.f + __expf(-acc)));
}

// ---------------- LayerNorm D=512 (wave per row) ----------------
__global__ void k_ln512(const u16* __restrict__ in1, const float* __restrict__ g,
                        const float* __restrict__ beta, u16* __restrict__ out) {
  int w = threadIdx.x >> 6, lane = threadIdx.x & 63;
  int row = blockIdx.x * 4 + w;
  bf8v v = *(const bf8v*)(in1 + (size_t)row * 512 + lane * 8);
  float x[8];
#pragma unroll
  for (int e = 0; e < 8; ++e) x[e] = bf2f((u16)v[e]);
  float s = 0.f, q = 0.f;
#pragma unroll
  for (int e = 0; e < 8; ++e) { s += x[e]; q += x[e] * x[e]; }
#pragma unroll
  for (int mm = 1; mm < 64; mm <<= 1) { s += __shfl_xor(s, mm); q += __shfl_xor(q, mm); }
  float mean = s / 512.f, var = q / 512.f - mean * mean;
  float rstd = rsqrtf(var + 1e-5f);
  bf8v ov;
#pragma unroll
  for (int e = 0; e < 8; ++e)
    ov[e] = (short)f2bf((x[e] - mean) * rstd * g[lane * 8 + e] + beta[lane * 8 + e]);
  *(bf8v*)(out + (size_t)row * 512 + lane * 8) = ov;
}

// ---------------- fused front chain: q_embed = LN2(pos + LN1(feat_pre)) ----------------
__global__ void k_ln_front(const u16* __restrict__ feat_pre, const u16* __restrict__ pos,
                           const float* __restrict__ g1, const float* __restrict__ b1,
                           const float* __restrict__ g2, const float* __restrict__ b2,
                           u16* __restrict__ out) {
  int w = threadIdx.x >> 6, lane = threadIdx.x & 63;
  int row = blockIdx.x * 4 + w;
  bf8v v = *(const bf8v*)(feat_pre + (size_t)row * 512 + lane * 8);
  float x[8];
#pragma unroll
  for (int e = 0; e < 8; ++e) x[e] = bf2f((u16)v[e]);
  float s = 0.f, q = 0.f;
#pragma unroll
  for (int e = 0; e < 8; ++e) { s += x[e]; q += x[e] * x[e]; }
#pragma unroll
  for (int mm = 1; mm < 64; mm <<= 1) { s += __shfl_xor(s, mm); q += __shfl_xor(q, mm); }
  float mean = s / 512.f, var = q / 512.f - mean * mean;
  float rstd = rsqrtf(var + 1e-5f);
  bf8v vp = *(const bf8v*)(pos + (size_t)row * 512 + lane * 8);
#pragma unroll
  for (int e = 0; e < 8; ++e)
    x[e] = (x[e] - mean) * rstd * g1[lane * 8 + e] + b1[lane * 8 + e] + bf2f((u16)vp[e]);
  s = 0.f; q = 0.f;
#pragma unroll
  for (int e = 0; e < 8; ++e) { s += x[e]; q += x[e] * x[e]; }
#pragma unroll
  for (int mm = 1; mm < 64; mm <<= 1) { s += __shfl_xor(s, mm); q += __shfl_xor(q, mm); }
  mean = s / 512.f; var = q / 512.f - mean * mean;
  rstd = rsqrtf(var + 1e-5f);
  bf8v ov;
#pragma unroll
  for (int e = 0; e < 8; ++e)
    ov[e] = (short)f2bf((x[e] - mean) * rstd * g2[lane * 8 + e] + b2[lane * 8 + e]);
  *(bf8v*)(out + (size_t)row * 512 + lane * 8) = ov;
}

// ---------------- fused geo LayerNorms (D=128): rows [0,4096) q-side, [4096,5120) k-side ----------------
__global__ void k_ln_geo(const u16* __restrict__ inq, const u16* __restrict__ ink,
                         const float* __restrict__ gq, const float* __restrict__ bq_,
                         const float* __restrict__ gk, const float* __restrict__ bk_,
                         u16* __restrict__ outq, u16* __restrict__ outk) {
  int w = threadIdx.x >> 6, lane = threadIdx.x & 63;
  int row = blockIdx.x * 4 + w;
  const u16* in; const float *g, *b; u16* out;
  if (row < 4096) { in = inq; g = gq; b = bq_; out = outq; }
  else { row -= 4096; in = ink; g = gk; b = bk_; out = outk; }
  uint32_t v = *(const uint32_t*)(in + (size_t)row * 128 + lane * 2);
  float x0 = bf2f((u16)(v & 0xffff)), x1 = bf2f((u16)(v >> 16));
  float s = x0 + x1, q = x0 * x0 + x1 * x1;
#pragma unroll
  for (int mm = 1; mm < 64; mm <<= 1) { s += __shfl_xor(s, mm); q += __shfl_xor(q, mm); }
  float mean = s / 128.f, var = q / 128.f - mean * mean;
  float rstd = rsqrtf(var + 1e-5f);
  u16 o0 = f2bf((x0 - mean) * rstd * g[lane * 2] + b[lane * 2]);
  u16 o1 = f2bf((x1 - mean) * rstd * g[lane * 2 + 1] + b[lane * 2 + 1]);
  *(uint32_t*)(out + (size_t)row * 128 + lane * 2) = (uint32_t)o0 | ((uint32_t)o1 << 16);
}

// ---------------- bf16 MFMA GEMM body, BK=64, dbuf LDS, global_load_lds + XOR swizzle ----------------
template <int BM, int BN>
__device__ __forceinline__ void gemm_body(const u16* __restrict__ A, const u16* __restrict__ W,
                                          const float* __restrict__ bias, u16* __restrict__ out,
                                          int m0, int n0, int N, int K) {
  constexpr int WTM = BM / 2, WTN = BN / 2;
  constexpr int MR = WTM / 16, NR = WTN / 16;
  __shared__ u16 sA[2][BM * 64];
  __shared__ u16 sB[2][BN * 64];
  const int tid = threadIdx.x, w = tid >> 6, lane = tid & 63;
  const int l16 = lane & 15, lh = lane >> 4;
  const int wr = w >> 1, wc = w & 1;

  f4v acc[MR][NR];
#pragma unroll
  for (int m = 0; m < MR; ++m)
#pragma unroll
    for (int j = 0; j < NR; ++j) acc[m][j] = (f4v){0.f, 0.f, 0.f, 0.f};

  auto stageA = [&](int buf, int k0) {
#pragma unroll
    for (int i = 0; i < BM * 8 / 256; ++i) {
      int c = i * 256 + tid;
      int row = c >> 3, cp = c & 7;
      int sc_ = cp ^ (row & 7);
      gld16(A + (size_t)(m0 + row) * K + k0 + sc_ * 8, &sA[buf][c * 8]);
    }
  };
  auto stageB = [&](int buf, int k0) {
#pragma unroll
    for (int i = 0; i < BN * 8 / 256; ++i) {
      int c = i * 256 + tid;
      int row = c >> 3, cp = c & 7;
      int sc_ = cp ^ (row & 7);
      gld16(W + (size_t)(n0 + row) * K + k0 + sc_ * 8, &sB[buf][c * 8]);
    }
  };

  stageA(0, 0); stageB(0, 0);
  __syncthreads();
  const int NK = K >> 6;
  for (int ks = 0; ks < NK; ++ks) {
    int nb = ks & 1;
    if (ks + 1 < NK) { stageA(nb ^ 1, (ks + 1) * 64); stageB(nb ^ 1, (ks + 1) * 64); }
#pragma unroll
    for (int kk = 0; kk < 2; ++kk) {
      bf8v af[MR], bfr[NR];
#pragma unroll
      for (int m = 0; m < MR; ++m) {
        int row = wr * WTM + m * 16 + l16;
        int cp = (kk * 4 + lh) ^ (row & 7);
        af[m] = *(const bf8v*)&sA[nb][row * 64 + cp * 8];
      }
#pragma unroll
      for (int j = 0; j < NR; ++j) {
        int row = wc * WTN + j * 16 + l16;
        int cp = (kk * 4 + lh) ^ (row & 7);
        bfr[j] = *(const bf8v*)&sB[nb][row * 64 + cp * 8];
      }
#pragma unroll
      for (int m = 0; m < MR; ++m)
#pragma unroll
        for (int j = 0; j < NR; ++j) acc[m][j] = mfma16(af[m], bfr[j], acc[m][j]);
    }
    __syncthreads();
  }
#pragma unroll
  for (int m = 0; m < MR; ++m) {
    int grow = m0 + wr * WTM + m * 16 + (lh << 2);
#pragma unroll
    for (int j = 0; j < NR; ++j) {
      int gcol = n0 + wc * WTN + j * 16 + l16;
      float bv = bias ? bias[gcol] : 0.f;
#pragma unroll
      for (int r = 0; r < 4; ++r)
        out[(size_t)(grow + r) * N + gcol] = f2bf(acc[m][j][r] + bv);
    }
  }
}

struct GP { const u16* A; const u16* W; const float* bias; u16* out; int K; };

// pos/feat z-batched GEMM (M=4096, N=512)
__global__ __launch_bounds__(256) void k_gemm_pf(GP g0, GP g1) {
  GP g = blockIdx.z ? g1 : g0;
  gemm_body<128, 64>(g.A, g.W, g.bias, g.out, blockIdx.x * 128, blockIdx.y * 64, 512, g.K);
}
// plain GEMM
__global__ __launch_bounds__(256) void k_gemm_plain(GP g, int N) {
  gemm_body<64, 64>(g.A, g.W, g.bias, g.out, blockIdx.x * 64, blockIdx.y * 64, N, g.K);
}
__global__ __launch_bounds__(256) void k_gemm_plain128(GP g, int N) {
  gemm_body<128, 64>(g.A, g.W, g.bias, g.out, blockIdx.x * 128, blockIdx.y * 64, N, g.K);
}
// concat-M GEMM for geo pairs: blocks [0, Mq/64) q-side, rest k-side (N=128, K=128)
__global__ __launch_bounds__(256) void k_gemm_cat(GP gq, GP gk, int Mq) {
  int bx = blockIdx.x;
  GP g; int m0;
  if (bx * 64 < Mq) { g = gq; m0 = bx * 64; } else { g = gk; m0 = bx * 64 - Mq; }
  gemm_body<64, 64>(g.A, g.W, g.bias, g.out, m0, blockIdx.y * 64, 128, g.K);
}

// ---------------- fused Q/K prep (rope + geo head + xy cross dims, bf16) ----------------
__global__ void k_qkprep_f(const u16* __restrict__ qlin, const u16* __restrict__ qglin,
                           const float* __restrict__ qxy, u16* __restrict__ Qaug_,
                           const u16* __restrict__ klin, const u16* __restrict__ kglin,
                           const float* __restrict__ kxy, u16* __restrict__ Kaug_,
                           float* __restrict__ kk2_) {
  int gid = blockIdx.x * 4 + (threadIdx.x >> 6);
  int lane = threadIdx.x & 63;
  const u16 *lin, *glin; const float* xy; u16* aug;
  int lstride, n, h, isQ; float scm, scg;
  if (gid < NF * 8) {
    lin = qlin; glin = qglin; xy = qxy; aug = Qaug_;
    lstride = MD; n = gid >> 3; h = gid & 7; isQ = 1;
    scm = 0.125f * L2E; scg = 0.25f * L2E;
  } else {
    gid -= NF * 8;
    lin = klin; glin = kglin; xy = kxy; aug = Kaug_;
    lstride = 1024; n = gid >> 3; h = gid & 7; isQ = 0;
    scm = 1.f; scg = 1.f;
  }
  float val = bf2f(lin[(size_t)n * lstride + h * 64 + lane]);
  float part = __shfl_xor(val, 8);
  float x = xy[n * 2], y = xy[n * 2 + 1];
  float outv = val;
  if (lane < 32) {
    float coord = (lane < 16) ? x : y;
    int j = lane & 7;
    float th = coord * __expf(-(float)j * 1.1512925465f);   // 10000^(-j/8)
    float sn, cs;
    __sincosf(th, &sn, &cs);
    outv = ((lane & 8) == 0) ? (val * cs - part * sn) : (part * sn + val * cs);
  }
  u16* dst = aug + (size_t)(h * (isQ ? NF : NS) + n) * DA;
  dst[lane] = f2bf(outv * scm);
  if (lane < 16) {
    float gv = bf2f(glin[(size_t)n * GHID + h * 16 + lane]);
    dst[64 + lane] = f2bf(gv * scg);
  } else if (lane == 16) {
    dst[80] = f2bf(S2L * x);
  } else if (lane == 17) {
    dst[81] = f2bf(S2L * y);
  } else if (lane == 18) {
    dst[82] = 0;
    if (!isQ && h == 0) kk2_[n] = L2E * (x * x + y * y);
  } else if (lane < 32) {
    dst[64 + lane] = 0;
  }
}

// ---------------- fused flash attention: single-buffer LDS, reg prefetch, defer-rescale ----------------
__global__ __launch_bounds__(256, 4) void k_flash(const u16* __restrict__ Qa,
                                                  const u16* __restrict__ Ka,
                                                  const u16* __restrict__ VT,
                                                  const float* __restrict__ kk2,
                                                  float* __restrict__ Opart,
                                                  float2* __restrict__ ml) {
  const int h = blockIdx.y, qb = blockIdx.x, sp = blockIdx.z;
  const int tid = threadIdx.x, w = tid >> 6, lane = tid & 63;
  const int l16 = lane & 15, lh = lane >> 4;
  __shared__ u16 sK[64][104];
  __shared__ u16 sV[64][72];
  __shared__ u16 sP[4][16][72];
  __shared__ float sKK[512];

  // stage this split's kk2 once
  ((float2*)sKK)[tid] = ((const float2*)(kk2 + sp * 512))[tid];

  const int qrow = qb * 64 + w * 16 + l16;
  bf8v qf[3];
#pragma unroll
  for (int c = 0; c < 3; ++c)
    qf[c] = *(const bf8v*)(Qa + (size_t)(h * NF + qrow) * DA + c * 32 + lh * 8);

  bf8v ONES;
#pragma unroll
  for (int i = 0; i < 8; ++i) ONES[i] = (short)0x3F80;

  const int crow = qb * 64 + w * 16 + (lh << 2);
  float m_run[4], l_run[4];
  f4v accO[4];
#pragma unroll
  for (int r = 0; r < 4; ++r) { m_run[r] = -1e30f; l_run[r] = 0.f; }
#pragma unroll
  for (int d = 0; d < 4; ++d) accO[d] = (f4v){0.f, 0.f, 0.f, 0.f};

  const int kt0 = sp * 8;
  bf8v kreg[3], vreg[2];
  auto sload = [&](int t8) {
    int kb = (kt0 + t8) * 64;
#pragma unroll
    for (int i = 0; i < 3; ++i) {
      int c = tid + i * 256; int r = c / 12, off = (c % 12) * 8;
      kreg[i] = *(const bf8v*)(Ka + ((size_t)(h * NS) + kb + r) * DA + off);
    }
#pragma unroll
    for (int i = 0; i < 2; ++i) {
      int c = tid + i * 256; int d = c >> 3, off = (c & 7) * 8;
      vreg[i] = *(const bf8v*)(VT + ((size_t)(h * HD) + d) * NS + kb + off);
    }
  };
  auto swrite = [&]() {
#pragma unroll
    for (int i = 0; i < 3; ++i) {
      int c = tid + i * 256; int r = c / 12, off = (c % 12) * 8;
      *(bf8v*)&sK[r][off] = kreg[i];
    }
#pragma unroll
    for (int i = 0; i < 2; ++i) {
      int c = tid + i * 256; int d = c >> 3, off = (c & 7) * 8;
      *(bf8v*)&sV[d][off] = vreg[i];
    }
  };

  sload(0); swrite();
  __syncthreads();
  for (int t8 = 0; t8 < 8; ++t8) {
    if (t8 < 7) sload(t8 + 1);    // next tile global->reg, lands during compute
    // ---- S = Qaug.Kaug - L2E*kk2  (exp2 domain) ----
    float p[4][4];
    float rmax[4] = {-1e30f, -1e30f, -1e30f, -1e30f};
#pragma unroll
    for (int j = 0; j < 4; ++j) {
      f4v s4 = (f4v){0.f, 0.f, 0.f, 0.f};
#pragma unroll
      for (int c = 0; c < 3; ++c) {
        bf8v kf = *(const bf8v*)&sK[j * 16 + l16][c * 32 + lh * 8];
        s4 = mfma16(qf[c], kf, s4);
      }
      float ck = sKK[t8 * 64 + j * 16 + l16];
#pragma unroll
      for (int r = 0; r < 4; ++r) {
        float sv = s4[r] - ck;
        p[j][r] = sv;
        rmax[r] = fmaxf(rmax[r], sv);
      }
    }
#pragma unroll
    for (int r = 0; r < 4; ++r)
#pragma unroll
      for (int mm = 1; mm < 16; mm <<= 1)
        rmax[r] = fmaxf(rmax[r], __shfl_xor(rmax[r], mm));
    // defer-rescale (T13): skip m/accO update when max growth bounded
    bool within = (rmax[0] <= m_run[0] + 8.f) && (rmax[1] <= m_run[1] + 8.f) &&
                  (rmax[2] <= m_run[2] + 8.f) && (rmax[3] <= m_run[3] + 8.f);
    if (!__all(within)) {
      float sc[4];
#pragma unroll
      for (int r = 0; r < 4; ++r) {
        float mnew = fmaxf(m_run[r], rmax[r]);
        sc[r] = exp2f(m_run[r] - mnew);
        m_run[r] = mnew;
      }
#pragma unroll
      for (int r = 0; r < 4; ++r) {
        l_run[r] *= sc[r];
#pragma unroll
        for (int d = 0; d < 4; ++d) accO[d][r] *= sc[r];
      }
    }
#pragma unroll
    for (int j = 0; j < 4; ++j)
#pragma unroll
      for (int r = 0; r < 4; ++r) {
        p[j][r] = exp2f(p[j][r] - m_run[r]);
        sP[w][(lh << 2) + r][j * 16 + l16] = f2bf(p[j][r]);
      }
    bf8v pf0 = *(const bf8v*)&sP[w][l16][lh * 8];
    bf8v pf1 = *(const bf8v*)&sP[w][l16][32 + lh * 8];
    f4v ls = (f4v){0.f, 0.f, 0.f, 0.f};
    ls = mfma16(pf0, ONES, ls);
    ls = mfma16(pf1, ONES, ls);
#pragma unroll
    for (int r = 0; r < 4; ++r) l_run[r] += ls[r];
#pragma unroll
    for (int c = 0; c < 2; ++c) {
      bf8v pf = (c == 0) ? pf0 : pf1;
#pragma unroll
      for (int d = 0; d < 4; ++d) {
        bf8v vf = *(const bf8v*)&sV[d * 16 + l16][c * 32 + lh * 8];
        accO[d] = mfma16(pf, vf, accO[d]);
      }
    }
    __syncthreads();              // all waves done reading sK/sV
    if (t8 < 7) swrite();         // regs -> LDS for next tile
    __syncthreads();
  }
  size_t obase = (size_t)(sp * 8 + h) * NF + crow;
#pragma unroll
  for (int d = 0; d < 4; ++d)
#pragma unroll
    for (int r = 0; r < 4; ++r)
      Opart[(obase + r) * 64 + d * 16 + l16] = accO[d][r];
  if (l16 == 0) {
#pragma unroll
    for (int r = 0; r < 4; ++r) ml[obase + r] = make_float2(m_run[r], l_run[r]);
  }
}

// ---------------- combine the 2 NS-splits (float4-vectorized) ----------------
__global__ void k_combine(const float* __restrict__ Opart, const float2* __restrict__ ml,
                          float* __restrict__ out) {
  int i4 = blockIdx.x * 256 + threadIdx.x;   // NF*MD/4 elements
  int n = i4 >> 7;                           // 128 float4 per row
  int c4 = i4 & 127, h = c4 >> 4, d4 = c4 & 15;
  float2 a = ml[(size_t)h * NF + n];
  float2 b = ml[(size_t)(8 + h) * NF + n];
  float m = fmaxf(a.x, b.x);
  float w1 = exp2f(a.x - m), w2 = exp2f(b.x - m);
  float rl = 1.f / (a.y * w1 + b.y * w2);
  float4 o1 = ((const float4*)(Opart + ((size_t)h * NF + n) * 64))[d4];
  float4 o2 = ((const float4*)(Opart + ((size_t)(8 + h) * NF + n) * 64))[d4];
  float4 r;
  r.x = (o1.x * w1 + o2.x * w2) * rl;
  r.y = (o1.y * w1 + o2.y * w2) * rl;
  r.z = (o1.z * w1 + o2.z * w2) * rl;
  r.w = (o1.w * w1 + o2.w * w2) * rl;
  ((float4*)out)[i4] = r;
}

extern "C" void kernel_launch(void* const* d_in, const int* in_sizes, int n_in,
                              void* d_out, int out_size, void* d_ws, size_t ws_size,
                              hipStream_t stream) {
  (void)in_sizes; (void)n_in; (void)out_size; (void)ws_size;
  const float* front_feat = (const float*)d_in[0];
  const float* bev_xy     = (const float*)d_in[1];
  const float* sat_tokens = (const float*)d_in[2];
  const float* sat_xy     = (const float*)d_in[3];
  const float* plucker    = (const float*)d_in[4];
  const float* pos_w1 = (const float*)d_in[5];
  const float* pos_b1 = (const float*)d_in[6];
  const float* pos_w2 = (const float*)d_in[7];
  const float* pos_b2 = (const float*)d_in[8];
  const float* fa_w   = (const float*)d_in[9];
  const float* fa_b   = (const float*)d_in[10];
  const float* fa_ln_g = (const float*)d_in[11];
  const float* fa_ln_b = (const float*)d_in[12];
  const float* qn_g   = (const float*)d_in[13];
  const float* qn_b   = (const float*)d_in[14];
  const float* sa_w   = (const float*)d_in[15];
  const float* sa_b   = (const float*)d_in[16];
  const float* sa_ln_g = (const float*)d_in[17];
  const float* sa_ln_b = (const float*)d_in[18];
  const float* wq = (const float*)d_in[19];
  const float* bq = (const float*)d_in[20];
  const float* wk = (const float*)d_in[21];
  const float* bk = (const float*)d_in[22];
  const float* wv = (const float*)d_in[23];
  const float* bv = (const float*)d_in[24];
  const float* plk_w1 = (const float*)d_in[25];
  const float* plk_b1 = (const float*)d_in[26];
  const float* plk_w2 = (const float*)d_in[27];
  const float* plk_b2 = (const float*)d_in[28];
  const float* sxy_w1 = (const float*)d_in[29];
  const float* sxy_b1 = (const float*)d_in[30];
  const float* sxy_w2 = (const float*)d_in[31];
  const float* sxy_b2 = (const float*)d_in[32];
  const float* gqn_g = (const float*)d_in[33];
  const float* gqn_b = (const float*)d_in[34];
  const float* gkn_g = (const float*)d_in[35];
  const float* gkn_b = (const float*)d_in[36];
  const float* wqg = (const float*)d_in[37];
  const float* bqg = (const float*)d_in[38];
  const float* wkg = (const float*)d_in[39];
  const float* bkg = (const float*)d_in[40];

  char* ws = (char*)d_ws;
  size_t off = 0;
  auto alloc = [&](size_t bytes) {
    size_t r = off;
    off += (bytes + 255) & ~(size_t)255;
    return r;
  };
  u16*   wpool   = (u16*)(ws + alloc((size_t)TOTW * 2));
  float* bkv     = (float*)(ws + alloc(1024 * 4));
  u16*   ffT     = (u16*)(ws + alloc((size_t)NF * 320 * 2));
  u16*   pos_h   = (u16*)(ws + alloc((size_t)NF * MD * 2));
  u16*   plk_h   = (u16*)(ws + alloc((size_t)NF * GHID * 2));
  u16*   sxy_h   = (u16*)(ws + alloc((size_t)NS * GHID * 2));
  u16*   pos     = (u16*)(ws + alloc((size_t)NF * MD * 2));
  u16*   feat_pre= (u16*)(ws + alloc((size_t)NF * MD * 2));
  u16*   satf_pre= (u16*)(ws + alloc((size_t)NS * MD * 2));
  u16*   satf    = (u16*)(ws + alloc((size_t)NS * MD * 2));
  u16*   q_embed = (u16*)(ws + alloc((size_t)NF * MD * 2));
  u16*   plk2    = (u16*)(ws + alloc((size_t)NF * GHID * 2));
  u16*   sxy2    = (u16*)(ws + alloc((size_t)NS * GHID * 2));
  u16*   q_lin   = (u16*)(ws + alloc((size_t)NF * MD * 2));
  u16*   kv_lin  = (u16*)(ws + alloc((size_t)NS * 1024 * 2));
  u16*   Qaug    = (u16*)(ws + alloc((size_t)8 * NF * DA * 2));
  u16*   Kaug    = (u16*)(ws + alloc((size_t)8 * NS * DA * 2));
  u16*   VT      = (u16*)(ws + alloc((size_t)8 * HD * NS * 2));
  float* kk2     = (float*)(ws + alloc((size_t)NS * 4));
  float* Opart   = (float*)(ws + alloc((size_t)2 * 8 * NF * 64 * 4));
  float2* mlb    = (float2*)(ws + alloc((size_t)2 * 8 * NF * 8));
  // aliases (producer dead before alias written)
  u16* plk_ln = plk_h;
  u16* sgf    = sxy_h;
  u16* qg_lin = plk2;
  u16* kg_lin = sxy2;

  dim3 b256(256);
  k_convert<<<dim3(TOTW / 4 / 256 + 1), b256, 0, stream>>>(
      pos_w2, fa_w, sa_w, wq, wk, wv, plk_w2, sxy_w2, wqg, wkg, sat_tokens,
      wpool, bk, bv, bkv);
  k_ffT<<<dim3(64, 10), b256, 0, stream>>>(front_feat, ffT);
  k_siluF<<<dim3(10752), b256, 0, stream>>>(bev_xy, pos_w1, pos_b1, pos_h,
                                            plucker, plk_w1, plk_b1, plk_h,
                                            sat_xy, sxy_w1, sxy_b1, sxy_h);

  GP gpos{pos_h, wpool + OFF_POSW2, pos_b2, pos, 512};
  GP gfeat{ffT, wpool + OFF_FAW, fa_b, feat_pre, 320};
  k_gemm_pf<<<dim3(NF / 128, MD / 64, 2), b256, 0, stream>>>(gpos, gfeat);
  GP gsat{wpool + OFF_SATT, wpool + OFF_SAW, sa_b, satf_pre, 768};
  k_gemm_plain<<<dim3(NS / 64, MD / 64), b256, 0, stream>>>(gsat, 512);
  GP ggq1{plk_h, wpool + OFF_PLKW2, plk_b2, plk2, 128};
  GP ggk1{sxy_h, wpool + OFF_SXYW2, sxy_b2, sxy2, 128};
  k_gemm_cat<<<dim3(80, 2), b256, 0, stream>>>(ggq1, ggk1, NF);

  k_ln_front<<<dim3(NF / 4), b256, 0, stream>>>(feat_pre, pos, fa_ln_g, fa_ln_b,
                                                qn_g, qn_b, q_embed);
  k_ln512<<<dim3(NS / 4), b256, 0, stream>>>(satf_pre, sa_ln_g, sa_ln_b, satf);
  k_ln_geo<<<dim3(5120 / 4), b256, 0, stream>>>(plk2, sxy2, gqn_g, gqn_b,
                                                gkn_g, gkn_b, plk_ln, sgf);

  GP gq{q_embed, wpool + OFF_WQ, bq, q_lin, 512};
  k_gemm_plain128<<<dim3(NF / 128, MD / 64), b256, 0, stream>>>(gq, 512);
  GP gkv{satf, wpool + OFF_WKV, bkv, kv_lin, 512};
  k_gemm_plain<<<dim3(NS / 64, 1024 / 64), b256, 0, stream>>>(gkv, 1024);
  GP ggq2{plk_ln, wpool + OFF_WQG, bqg, qg_lin, 128};
  GP ggk2{sgf, wpool + OFF_WKG, bkg, kg_lin, 128};
  k_gemm_cat<<<dim3(80, 2), b256, 0, stream>>>(ggq2, ggk2, NF);

  k_qkprep_f<<<dim3((NF * 8 + NS * 8) / 4), b256, 0, stream>>>(
      q_lin, qg_lin, bev_xy, Qaug, kv_lin, kg_lin, sat_xy, Kaug, kk2);
  k_vt<<<dim3(NS / 64, 8), b256, 0, stream>>>(kv_lin, VT);

  k_flash<<<dim3(NF / 64, 8, 2), b256, 0, stream>>>(Qaug, Kaug, VT, kk2, Opart, mlb);
  k_combine<<<dim3(NF * MD / 4 / 256), b256, 0, stream>>>(Opart, mlb, (float*)d_out);
}

// Round 5
// 92.631 us; speedup vs baseline: 2.5200x; 1.3473x over previous
//
#include <hip/hip_runtime.h>
#include <hip/hip_bf16.h>
#include <stdint.h>

// Problem constants
#define NF 4096
#define NS 1024
#define MD 512
#define HD 64
#define DA 96
#define GHID 128

#define L2E 1.44269504f          // log2(e)
#define S2L 1.6986436f           // sqrt(2*log2e)  (LAMBDA_GEO=1)

typedef unsigned short u16;
typedef __attribute__((ext_vector_type(8))) short bf8v;   // 8 bf16
typedef __attribute__((ext_vector_type(4))) float f4v;

__device__ __forceinline__ u16 f2bf(float f) {
  __hip_bfloat16 h = __float2bfloat16(f);
  return __builtin_bit_cast(u16, h);
}
__device__ __forceinline__ float bf2f(u16 u) {
  union { unsigned u; float f; } v; v.u = ((unsigned)u) << 16; return v.f;
}
__device__ __forceinline__ f4v mfma16(bf8v a, bf8v b, f4v c) {
  return __builtin_amdgcn_mfma_f32_16x16x32_bf16(a, b, c, 0, 0, 0);
}
__device__ __forceinline__ void gld16(const void* g, void* l) {
  __builtin_amdgcn_global_load_lds(
      (const __attribute__((address_space(1))) unsigned int*)g,
      (__attribute__((address_space(3))) unsigned int*)l, 16, 0, 0);
}

// weight pool offsets (bf16 elements)
#define OFF_POSW2 0
#define OFF_FAW   262144
#define OFF_SAW   425984
#define OFF_WQ    819200
#define OFF_WKV   1081344
#define OFF_PLKW2 1605632
#define OFF_SXYW2 1622016
#define OFF_WQG   1638400
#define OFF_WKG   1654784
#define OFF_SATT  1671168
#define TOTW      2457600

// ================= L0: convert weights + ffT transpose + 3 silu MLPs =================
// blocks: [0,2401) convert, [2401,3041) ffT, [3041,13793) silu
__global__ __launch_bounds__(256) void k_l0(
    const float* __restrict__ s0, const float* __restrict__ s1,
    const float* __restrict__ s2, const float* __restrict__ s3,
    const float* __restrict__ s4, const float* __restrict__ s5,
    const float* __restrict__ s6, const float* __restrict__ s7,
    const float* __restrict__ s8, const float* __restrict__ s9,
    const float* __restrict__ s10, u16* __restrict__ pool,
    const float* __restrict__ bk, const float* __restrict__ bv,
    float* __restrict__ bkv,
    const float* __restrict__ ff, u16* __restrict__ ffT,
    const float* __restrict__ in0, const float* __restrict__ w0,
    const float* __restrict__ b0, u16* __restrict__ o0,
    const float* __restrict__ in1, const float* __restrict__ w1,
    const float* __restrict__ b1, u16* __restrict__ o1,
    const float* __restrict__ in2, const float* __restrict__ w2,
    const float* __restrict__ b2, u16* __restrict__ o2) {
  __shared__ u16 sT[32][72];
  int blk = blockIdx.x, t = threadIdx.x;
  if (blk < 2401) {
    int i4 = blk * 256 + t;
    if (i4 < TOTW / 4) {
      int idx = i4 * 4;
      const float* src; int off;
      if      (idx < OFF_FAW)   { src = s0;  off = OFF_POSW2; }
      else if (idx < OFF_SAW)   { src = s1;  off = OFF_FAW; }
      else if (idx < OFF_WQ)    { src = s2;  off = OFF_SAW; }
      else if (idx < OFF_WKV)   { src = s3;  off = OFF_WQ; }
      else if (idx < 1343488)   { src = s4;  off = OFF_WKV; }
      else if (idx < OFF_PLKW2) { src = s5;  off = 1343488; }
      else if (idx < OFF_SXYW2) { src = s6;  off = OFF_PLKW2; }
      else if (idx < OFF_WQG)   { src = s7;  off = OFF_SXYW2; }
      else if (idx < OFF_WKG)   { src = s8;  off = OFF_WQG; }
      else if (idx < OFF_SATT)  { src = s9;  off = OFF_WKG; }
      else                      { src = s10; off = OFF_SATT; }
      float4 v = *(const float4*)(src + (idx - off));
      ushort4 o;
      o.x = f2bf(v.x); o.y = f2bf(v.y); o.z = f2bf(v.z); o.w = f2bf(v.w);
      *(ushort4*)(pool + idx) = o;
    } else if (i4 < TOTW / 4 + 256) {
      int j = (i4 - TOTW / 4) * 4;
#pragma unroll
      for (int e = 0; e < 4; ++e) {
        int b = j + e;
        bkv[b] = (b < 512) ? bk[b] : bv[b - 512];
      }
    }
  } else if (blk < 3041) {
    int lb = blk - 2401;
    int n0 = (lb & 63) * 64, c0 = (lb >> 6) * 32;
    {
      int cr = t >> 3, nc = (t & 7) * 8;
      const float* src = ff + (size_t)(c0 + cr) * NF + n0 + nc;
      float4 v0 = *(const float4*)src, v1 = *(const float4*)(src + 4);
      bf8v p;
      p[0]=(short)f2bf(v0.x); p[1]=(short)f2bf(v0.y); p[2]=(short)f2bf(v0.z); p[3]=(short)f2bf(v0.w);
      p[4]=(short)f2bf(v1.x); p[5]=(short)f2bf(v1.y); p[6]=(short)f2bf(v1.z); p[7]=(short)f2bf(v1.w);
      *(bf8v*)&sT[cr][nc] = p;
    }
    __syncthreads();
    {
      int r = t >> 2, cc = (t & 3) * 8;
      bf8v p;
#pragma unroll
      for (int e = 0; e < 8; ++e) p[e] = (short)sT[cc + e][r];
      *(bf8v*)(ffT + (size_t)(n0 + r) * 320 + c0 + cc) = p;
    }
  } else {
    int lb = blk - 3041;
    const float *in, *w, *b; u16* o; int mlog, K, idx;
    if (lb < 8192)       { in = in0; w = w0; b = b0; o = o0; mlog = 9; K = 2; idx = lb * 256 + t; }
    else if (lb < 10240) { in = in1; w = w1; b = b1; o = o1; mlog = 7; K = 6; idx = (lb - 8192) * 256 + t; }
    else                 { in = in2; w = w2; b = b2; o = o2; mlog = 7; K = 2; idx = (lb - 10240) * 256 + t; }
    int M = 1 << mlog;
    int n = idx >> mlog, m = idx & (M - 1);
    float acc = b[m];
    for (int k = 0; k < K; ++k) acc += in[n * K + k] * w[m * K + k];
    o[idx] = f2bf(acc / (1.f + __expf(-acc)));
  }
}

// ================= bf16 MFMA GEMM body, 64x64 tile, BK=64, dbuf LDS =================
__device__ __forceinline__ void gemm_body(const u16* __restrict__ A, const u16* __restrict__ W,
                                          const float* __restrict__ bias, u16* __restrict__ out,
                                          int m0, int n0, int N, int K) {
  constexpr int BM = 64, BN = 64;
  constexpr int MR = 2, NR = 2;        // per-wave 32x32
  __shared__ u16 sA[2][BM * 64];
  __shared__ u16 sB[2][BN * 64];
  const int tid = threadIdx.x, w = tid >> 6, lane = tid & 63;
  const int l16 = lane & 15, lh = lane >> 4;
  const int wr = w >> 1, wc = w & 1;

  f4v acc[MR][NR];
#pragma unroll
  for (int m = 0; m < MR; ++m)
#pragma unroll
    for (int j = 0; j < NR; ++j) acc[m][j] = (f4v){0.f, 0.f, 0.f, 0.f};

  auto stageA = [&](int buf, int k0) {
#pragma unroll
    for (int i = 0; i < 2; ++i) {
      int c = i * 256 + tid;
      int row = c >> 3, cp = c & 7;
      int sc_ = cp ^ (row & 7);
      gld16(A + (size_t)(m0 + row) * K + k0 + sc_ * 8, &sA[buf][c * 8]);
    }
  };
  auto stageB = [&](int buf, int k0) {
#pragma unroll
    for (int i = 0; i < 2; ++i) {
      int c = i * 256 + tid;
      int row = c >> 3, cp = c & 7;
      int sc_ = cp ^ (row & 7);
      gld16(W + (size_t)(n0 + row) * K + k0 + sc_ * 8, &sB[buf][c * 8]);
    }
  };

  stageA(0, 0); stageB(0, 0);
  __syncthreads();
  const int NK = K >> 6;
  for (int ks = 0; ks < NK; ++ks) {
    int nb = ks & 1;
    if (ks + 1 < NK) { stageA(nb ^ 1, (ks + 1) * 64); stageB(nb ^ 1, (ks + 1) * 64); }
#pragma unroll
    for (int kk = 0; kk < 2; ++kk) {
      bf8v af[MR], bfr[NR];
#pragma unroll
      for (int m = 0; m < MR; ++m) {
        int row = wr * 32 + m * 16 + l16;
        int cp = (kk * 4 + lh) ^ (row & 7);
        af[m] = *(const bf8v*)&sA[nb][row * 64 + cp * 8];
      }
#pragma unroll
      for (int j = 0; j < NR; ++j) {
        int row = wc * 32 + j * 16 + l16;
        int cp = (kk * 4 + lh) ^ (row & 7);
        bfr[j] = *(const bf8v*)&sB[nb][row * 64 + cp * 8];
      }
#pragma unroll
      for (int m = 0; m < MR; ++m)
#pragma unroll
        for (int j = 0; j < NR; ++j) acc[m][j] = mfma16(af[m], bfr[j], acc[m][j]);
    }
    __syncthreads();
  }
#pragma unroll
  for (int m = 0; m < MR; ++m) {
    int grow = m0 + wr * 32 + m * 16 + (lh << 2);
#pragma unroll
    for (int j = 0; j < NR; ++j) {
      int gcol = n0 + wc * 32 + j * 16 + l16;
      float bv = bias ? bias[gcol] : 0.f;
#pragma unroll
      for (int r = 0; r < 4; ++r)
        out[(size_t)(grow + r) * N + gcol] = f2bf(acc[m][j][r] + bv);
    }
  }
}

struct GP { const u16* A; const u16* W; const float* bias; u16* out; int K; int N; int M; };

__device__ __forceinline__ void gemm_dispatch(const GP& g, int blk) {
  int mt = g.M >> 6;
  int m0 = (blk % mt) * 64, n0 = (blk / mt) * 64;
  gemm_body(g.A, g.W, g.bias, g.out, m0, n0, g.N, g.K);
}

// L1: pos(512) feat(512) sat(128) geo1q(128) geo1k(32) = 1312 blocks
__global__ __launch_bounds__(256) void k_gemm_L1(GP a, GP b, GP c, GP d, GP e) {
  int blk = blockIdx.x;
  if (blk < 512)       gemm_dispatch(a, blk);
  else if (blk < 1024) gemm_dispatch(b, blk - 512);
  else if (blk < 1152) gemm_dispatch(c, blk - 1024);
  else if (blk < 1280) gemm_dispatch(d, blk - 1152);
  else                 gemm_dispatch(e, blk - 1280);
}
// L2: q(512) kv(256) geo2q(128) geo2k(32) = 928 blocks
__global__ __launch_bounds__(256) void k_gemm_L2(GP a, GP b, GP c, GP d) {
  int blk = blockIdx.x;
  if (blk < 512)      gemm_dispatch(a, blk);
  else if (blk < 768) gemm_dispatch(b, blk - 512);
  else if (blk < 896) gemm_dispatch(c, blk - 768);
  else                gemm_dispatch(d, blk - 896);
}

// ================= merged LayerNorms =================
// blocks: [0,1024) front chain, [1024,1280) sat D=512, [1280,2560) geo D=128
__global__ __launch_bounds__(256) void k_ln_all(
    const u16* __restrict__ feat_pre, const u16* __restrict__ pos,
    const float* __restrict__ fg, const float* __restrict__ fb,
    const float* __restrict__ qg, const float* __restrict__ qb2,
    u16* __restrict__ q_embed,
    const u16* __restrict__ satf_pre, const float* __restrict__ sg,
    const float* __restrict__ sb, u16* __restrict__ satf,
    const u16* __restrict__ ginq, const u16* __restrict__ gink,
    const float* __restrict__ ggq, const float* __restrict__ gbq,
    const float* __restrict__ ggk, const float* __restrict__ gbk,
    u16* __restrict__ goutq, u16* __restrict__ goutk) {
  int blk = blockIdx.x;
  int w = threadIdx.x >> 6, lane = threadIdx.x & 63;
  if (blk < 1024) {
    int row = blk * 4 + w;
    bf8v v = *(const bf8v*)(feat_pre + (size_t)row * 512 + lane * 8);
    float x[8];
#pragma unroll
    for (int e = 0; e < 8; ++e) x[e] = bf2f((u16)v[e]);
    float s = 0.f, q = 0.f;
#pragma unroll
    for (int e = 0; e < 8; ++e) { s += x[e]; q += x[e] * x[e]; }
#pragma unroll
    for (int mm = 1; mm < 64; mm <<= 1) { s += __shfl_xor(s, mm); q += __shfl_xor(q, mm); }
    float mean = s / 512.f, var = q / 512.f - mean * mean;
    float rstd = rsqrtf(var + 1e-5f);
    bf8v vp = *(const bf8v*)(pos + (size_t)row * 512 + lane * 8);
#pragma unroll
    for (int e = 0; e < 8; ++e)
      x[e] = (x[e] - mean) * rstd * fg[lane * 8 + e] + fb[lane * 8 + e] + bf2f((u16)vp[e]);
    s = 0.f; q = 0.f;
#pragma unroll
    for (int e = 0; e < 8; ++e) { s += x[e]; q += x[e] * x[e]; }
#pragma unroll
    for (int mm = 1; mm < 64; mm <<= 1) { s += __shfl_xor(s, mm); q += __shfl_xor(q, mm); }
    mean = s / 512.f; var = q / 512.f - mean * mean;
    rstd = rsqrtf(var + 1e-5f);
    bf8v ov;
#pragma unroll
    for (int e = 0; e < 8; ++e)
      ov[e] = (short)f2bf((x[e] - mean) * rstd * qg[lane * 8 + e] + qb2[lane * 8 + e]);
    *(bf8v*)(q_embed + (size_t)row * 512 + lane * 8) = ov;
  } else if (blk < 1280) {
    int row = (blk - 1024) * 4 + w;
    bf8v v = *(const bf8v*)(satf_pre + (size_t)row * 512 + lane * 8);
    float x[8];
#pragma unroll
    for (int e = 0; e < 8; ++e) x[e] = bf2f((u16)v[e]);
    float s = 0.f, q = 0.f;
#pragma unroll
    for (int e = 0; e < 8; ++e) { s += x[e]; q += x[e] * x[e]; }
#pragma unroll
    for (int mm = 1; mm < 64; mm <<= 1) { s += __shfl_xor(s, mm); q += __shfl_xor(q, mm); }
    float mean = s / 512.f, var = q / 512.f - mean * mean;
    float rstd = rsqrtf(var + 1e-5f);
    bf8v ov;
#pragma unroll
    for (int e = 0; e < 8; ++e)
      ov[e] = (short)f2bf((x[e] - mean) * rstd * sg[lane * 8 + e] + sb[lane * 8 + e]);
    *(bf8v*)(satf + (size_t)row * 512 + lane * 8) = ov;
  } else {
    int row = (blk - 1280) * 4 + w;
    const u16* in; const float *g, *b; u16* out;
    if (row < 4096) { in = ginq; g = ggq; b = gbq; out = goutq; }
    else { row -= 4096; in = gink; g = ggk; b = gbk; out = goutk; }
    uint32_t v = *(const uint32_t*)(in + (size_t)row * 128 + lane * 2);
    float x0 = bf2f((u16)(v & 0xffff)), x1 = bf2f((u16)(v >> 16));
    float s = x0 + x1, q = x0 * x0 + x1 * x1;
#pragma unroll
    for (int mm = 1; mm < 64; mm <<= 1) { s += __shfl_xor(s, mm); q += __shfl_xor(q, mm); }
    float mean = s / 128.f, var = q / 128.f - mean * mean;
    float rstd = rsqrtf(var + 1e-5f);
    u16 o0 = f2bf((x0 - mean) * rstd * g[lane * 2] + b[lane * 2]);
    u16 o1 = f2bf((x1 - mean) * rstd * g[lane * 2 + 1] + b[lane * 2 + 1]);
    *(uint32_t*)(out + (size_t)row * 128 + lane * 2) = (uint32_t)o0 | ((uint32_t)o1 << 16);
  }
}

// ================= merged prep: Q/K aug (rope+geo+xy) + V transpose =================
// blocks: [0,10240) qkprep, [10240,10368) vt
__global__ __launch_bounds__(256) void k_prep(
    const u16* __restrict__ qlin, const u16* __restrict__ qglin,
    const float* __restrict__ qxy, u16* __restrict__ Qaug_,
    const u16* __restrict__ klin, const u16* __restrict__ kglin,
    const float* __restrict__ kxy, u16* __restrict__ Kaug_,
    float* __restrict__ kk2_, u16* __restrict__ VT) {
  __shared__ u16 sT[64][72];
  int blk = blockIdx.x;
  if (blk < 10240) {
    int gid = blk * 4 + (threadIdx.x >> 6);
    int lane = threadIdx.x & 63;
    const u16 *lin, *glin; const float* xy; u16* aug;
    int lstride, n, h, isQ; float scm, scg;
    if (gid < NF * 8) {
      lin = qlin; glin = qglin; xy = qxy; aug = Qaug_;
      lstride = MD; n = gid >> 3; h = gid & 7; isQ = 1;
      scm = 0.125f * L2E; scg = 0.25f * L2E;
    } else {
      gid -= NF * 8;
      lin = klin; glin = kglin; xy = kxy; aug = Kaug_;
      lstride = 1024; n = gid >> 3; h = gid & 7; isQ = 0;
      scm = 1.f; scg = 1.f;
    }
    float val = bf2f(lin[(size_t)n * lstride + h * 64 + lane]);
    float part = __shfl_xor(val, 8);
    float x = xy[n * 2], y = xy[n * 2 + 1];
    float outv = val;
    if (lane < 32) {
      float coord = (lane < 16) ? x : y;
      int j = lane & 7;
      float th = coord * __expf(-(float)j * 1.1512925465f);   // 10000^(-j/8)
      float sn, cs;
      __sincosf(th, &sn, &cs);
      outv = ((lane & 8) == 0) ? (val * cs - part * sn) : (part * sn + val * cs);
    }
    u16* dst = aug + (size_t)(h * (isQ ? NF : NS) + n) * DA;
    dst[lane] = f2bf(outv * scm);
    if (lane < 16) {
      float gv = bf2f(glin[(size_t)n * GHID + h * 16 + lane]);
      dst[64 + lane] = f2bf(gv * scg);
    } else if (lane == 16) {
      dst[80] = f2bf(S2L * x);
    } else if (lane == 17) {
      dst[81] = f2bf(S2L * y);
    } else if (lane == 18) {
      dst[82] = 0;
      if (!isQ && h == 0) kk2_[n] = L2E * (x * x + y * y);
    } else if (lane < 32) {
      dst[64 + lane] = 0;
    }
  } else {
    int lb = blk - 10240;
    int n0 = (lb & 15) * 64, h = lb >> 4;
    int t = threadIdx.x;
    int r = t >> 2, c = (t & 3) * 16;
    const u16* src = klin + (size_t)(n0 + r) * 1024 + 512 + h * 64 + c;
    *(bf8v*)&sT[r][c]     = *(const bf8v*)src;
    *(bf8v*)&sT[r][c + 8] = *(const bf8v*)(src + 8);
    __syncthreads();
    int d = t >> 2, nc = (t & 3) * 16;
    bf8v p0, p1;
#pragma unroll
    for (int e = 0; e < 8; ++e) { p0[e] = (short)sT[nc + e][d]; p1[e] = (short)sT[nc + 8 + e][d]; }
    u16* dst = VT + (size_t)(h * 64 + d) * 1024 + n0 + nc;
    *(bf8v*)dst = p0;
    *(bf8v*)(dst + 8) = p1;
  }
}

// ================= fused flash attention (unchanged from r4) =================
__global__ __launch_bounds__(256, 4) void k_flash(const u16* __restrict__ Qa,
                                                  const u16* __restrict__ Ka,
                                                  const u16* __restrict__ VT,
                                                  const float* __restrict__ kk2,
                                                  float* __restrict__ Opart,
                                                  float2* __restrict__ ml) {
  const int h = blockIdx.y, qb = blockIdx.x, sp = blockIdx.z;
  const int tid = threadIdx.x, w = tid >> 6, lane = tid & 63;
  const int l16 = lane & 15, lh = lane >> 4;
  __shared__ u16 sK[64][104];
  __shared__ u16 sV[64][72];
  __shared__ u16 sP[4][16][72];
  __shared__ float sKK[512];

  ((float2*)sKK)[tid] = ((const float2*)(kk2 + sp * 512))[tid];

  const int qrow = qb * 64 + w * 16 + l16;
  bf8v qf[3];
#pragma unroll
  for (int c = 0; c < 3; ++c)
    qf[c] = *(const bf8v*)(Qa + (size_t)(h * NF + qrow) * DA + c * 32 + lh * 8);

  bf8v ONES;
#pragma unroll
  for (int i = 0; i < 8; ++i) ONES[i] = (short)0x3F80;

  const int crow = qb * 64 + w * 16 + (lh << 2);
  float m_run[4], l_run[4];
  f4v accO[4];
#pragma unroll
  for (int r = 0; r < 4; ++r) { m_run[r] = -1e30f; l_run[r] = 0.f; }
#pragma unroll
  for (int d = 0; d < 4; ++d) accO[d] = (f4v){0.f, 0.f, 0.f, 0.f};

  const int kt0 = sp * 8;
  bf8v kreg[3], vreg[2];
  auto sload = [&](int t8) {
    int kb = (kt0 + t8) * 64;
#pragma unroll
    for (int i = 0; i < 3; ++i) {
      int c = tid + i * 256; int r = c / 12, off = (c % 12) * 8;
      kreg[i] = *(const bf8v*)(Ka + ((size_t)(h * NS) + kb + r) * DA + off);
    }
#pragma unroll
    for (int i = 0; i < 2; ++i) {
      int c = tid + i * 256; int d = c >> 3, off = (c & 7) * 8;
      vreg[i] = *(const bf8v*)(VT + ((size_t)(h * HD) + d) * NS + kb + off);
    }
  };
  auto swrite = [&]() {
#pragma unroll
    for (int i = 0; i < 3; ++i) {
      int c = tid + i * 256; int r = c / 12, off = (c % 12) * 8;
      *(bf8v*)&sK[r][off] = kreg[i];
    }
#pragma unroll
    for (int i = 0; i < 2; ++i) {
      int c = tid + i * 256; int d = c >> 3, off = (c & 7) * 8;
      *(bf8v*)&sV[d][off] = vreg[i];
    }
  };

  sload(0); swrite();
  __syncthreads();
  for (int t8 = 0; t8 < 8; ++t8) {
    if (t8 < 7) sload(t8 + 1);
    float p[4][4];
    float rmax[4] = {-1e30f, -1e30f, -1e30f, -1e30f};
#pragma unroll
    for (int j = 0; j < 4; ++j) {
      f4v s4 = (f4v){0.f, 0.f, 0.f, 0.f};
#pragma unroll
      for (int c = 0; c < 3; ++c) {
        bf8v kf = *(const bf8v*)&sK[j * 16 + l16][c * 32 + lh * 8];
        s4 = mfma16(qf[c], kf, s4);
      }
      float ck = sKK[t8 * 64 + j * 16 + l16];
#pragma unroll
      for (int r = 0; r < 4; ++r) {
        float sv = s4[r] - ck;
        p[j][r] = sv;
        rmax[r] = fmaxf(rmax[r], sv);
      }
    }
#pragma unroll
    for (int r = 0; r < 4; ++r)
#pragma unroll
      for (int mm = 1; mm < 16; mm <<= 1)
        rmax[r] = fmaxf(rmax[r], __shfl_xor(rmax[r], mm));
    bool within = (rmax[0] <= m_run[0] + 8.f) && (rmax[1] <= m_run[1] + 8.f) &&
                  (rmax[2] <= m_run[2] + 8.f) && (rmax[3] <= m_run[3] + 8.f);
    if (!__all(within)) {
      float sc[4];
#pragma unroll
      for (int r = 0; r < 4; ++r) {
        float mnew = fmaxf(m_run[r], rmax[r]);
        sc[r] = exp2f(m_run[r] - mnew);
        m_run[r] = mnew;
      }
#pragma unroll
      for (int r = 0; r < 4; ++r) {
        l_run[r] *= sc[r];
#pragma unroll
        for (int d = 0; d < 4; ++d) accO[d][r] *= sc[r];
      }
    }
#pragma unroll
    for (int j = 0; j < 4; ++j)
#pragma unroll
      for (int r = 0; r < 4; ++r) {
        p[j][r] = exp2f(p[j][r] - m_run[r]);
        sP[w][(lh << 2) + r][j * 16 + l16] = f2bf(p[j][r]);
      }
    bf8v pf0 = *(const bf8v*)&sP[w][l16][lh * 8];
    bf8v pf1 = *(const bf8v*)&sP[w][l16][32 + lh * 8];
    f4v ls = (f4v){0.f, 0.f, 0.f, 0.f};
    ls = mfma16(pf0, ONES, ls);
    ls = mfma16(pf1, ONES, ls);
#pragma unroll
    for (int r = 0; r < 4; ++r) l_run[r] += ls[r];
#pragma unroll
    for (int c = 0; c < 2; ++c) {
      bf8v pf = (c == 0) ? pf0 : pf1;
#pragma unroll
      for (int d = 0; d < 4; ++d) {
        bf8v vf = *(const bf8v*)&sV[d * 16 + l16][c * 32 + lh * 8];
        accO[d] = mfma16(pf, vf, accO[d]);
      }
    }
    __syncthreads();
    if (t8 < 7) swrite();
    __syncthreads();
  }
  size_t obase = (size_t)(sp * 8 + h) * NF + crow;
#pragma unroll
  for (int d = 0; d < 4; ++d)
#pragma unroll
    for (int r = 0; r < 4; ++r)
      Opart[(obase + r) * 64 + d * 16 + l16] = accO[d][r];
  if (l16 == 0) {
#pragma unroll
    for (int r = 0; r < 4; ++r) ml[obase + r] = make_float2(m_run[r], l_run[r]);
  }
}

// ================= combine the 2 NS-splits =================
__global__ void k_combine(const float* __restrict__ Opart, const float2* __restrict__ ml,
                          float* __restrict__ out) {
  int i4 = blockIdx.x * 256 + threadIdx.x;
  int n = i4 >> 7;
  int c4 = i4 & 127, h = c4 >> 4, d4 = c4 & 15;
  float2 a = ml[(size_t)h * NF + n];
  float2 b = ml[(size_t)(8 + h) * NF + n];
  float m = fmaxf(a.x, b.x);
  float w1 = exp2f(a.x - m), w2 = exp2f(b.x - m);
  float rl = 1.f / (a.y * w1 + b.y * w2);
  float4 o1 = ((const float4*)(Opart + ((size_t)h * NF + n) * 64))[d4];
  float4 o2 = ((const float4*)(Opart + ((size_t)(8 + h) * NF + n) * 64))[d4];
  float4 r;
  r.x = (o1.x * w1 + o2.x * w2) * rl;
  r.y = (o1.y * w1 + o2.y * w2) * rl;
  r.z = (o1.z * w1 + o2.z * w2) * rl;
  r.w = (o1.w * w1 + o2.w * w2) * rl;
  ((float4*)out)[i4] = r;
}

extern "C" void kernel_launch(void* const* d_in, const int* in_sizes, int n_in,
                              void* d_out, int out_size, void* d_ws, size_t ws_size,
                              hipStream_t stream) {
  (void)in_sizes; (void)n_in; (void)out_size; (void)ws_size;
  const float* front_feat = (const float*)d_in[0];
  const float* bev_xy     = (const float*)d_in[1];
  const float* sat_tokens = (const float*)d_in[2];
  const float* sat_xy     = (const float*)d_in[3];
  const float* plucker    = (const float*)d_in[4];
  const float* pos_w1 = (const float*)d_in[5];
  const float* pos_b1 = (const float*)d_in[6];
  const float* pos_w2 = (const float*)d_in[7];
  const float* pos_b2 = (const float*)d_in[8];
  const float* fa_w   = (const float*)d_in[9];
  const float* fa_b   = (const float*)d_in[10];
  const float* fa_ln_g = (const float*)d_in[11];
  const float* fa_ln_b = (const float*)d_in[12];
  const float* qn_g   = (const float*)d_in[13];
  const float* qn_b   = (const float*)d_in[14];
  const float* sa_w   = (const float*)d_in[15];
  const float* sa_b   = (const float*)d_in[16];
  const float* sa_ln_g = (const float*)d_in[17];
  const float* sa_ln_b = (const float*)d_in[18];
  const float* wq = (const float*)d_in[19];
  const float* bq = (const float*)d_in[20];
  const float* wk = (const float*)d_in[21];
  const float* bk = (const float*)d_in[22];
  const float* wv = (const float*)d_in[23];
  const float* bv = (const float*)d_in[24];
  const float* plk_w1 = (const float*)d_in[25];
  const float* plk_b1 = (const float*)d_in[26];
  const float* plk_w2 = (const float*)d_in[27];
  const float* plk_b2 = (const float*)d_in[28];
  const float* sxy_w1 = (const float*)d_in[29];
  const float* sxy_b1 = (const float*)d_in[30];
  const float* sxy_w2 = (const float*)d_in[31];
  const float* sxy_b2 = (const float*)d_in[32];
  const float* gqn_g = (const float*)d_in[33];
  const float* gqn_b = (const float*)d_in[34];
  const float* gkn_g = (const float*)d_in[35];
  const float* gkn_b = (const float*)d_in[36];
  const float* wqg = (const float*)d_in[37];
  const float* bqg = (const float*)d_in[38];
  const float* wkg = (const float*)d_in[39];
  const float* bkg = (const float*)d_in[40];

  char* ws = (char*)d_ws;
  size_t off = 0;
  auto alloc = [&](size_t bytes) {
    size_t r = off;
    off += (bytes + 255) & ~(size_t)255;
    return r;
  };
  u16*   wpool   = (u16*)(ws + alloc((size_t)TOTW * 2));
  float* bkv     = (float*)(ws + alloc(1024 * 4));
  u16*   ffT     = (u16*)(ws + alloc((size_t)NF * 320 * 2));
  u16*   pos_h   = (u16*)(ws + alloc((size_t)NF * MD * 2));
  u16*   plk_h   = (u16*)(ws + alloc((size_t)NF * GHID * 2));
  u16*   sxy_h   = (u16*)(ws + alloc((size_t)NS * GHID * 2));
  u16*   pos     = (u16*)(ws + alloc((size_t)NF * MD * 2));
  u16*   feat_pre= (u16*)(ws + alloc((size_t)NF * MD * 2));
  u16*   satf_pre= (u16*)(ws + alloc((size_t)NS * MD * 2));
  u16*   satf    = (u16*)(ws + alloc((size_t)NS * MD * 2));
  u16*   q_embed = (u16*)(ws + alloc((size_t)NF * MD * 2));
  u16*   plk2    = (u16*)(ws + alloc((size_t)NF * GHID * 2));
  u16*   sxy2    = (u16*)(ws + alloc((size_t)NS * GHID * 2));
  u16*   q_lin   = (u16*)(ws + alloc((size_t)NF * MD * 2));
  u16*   kv_lin  = (u16*)(ws + alloc((size_t)NS * 1024 * 2));
  u16*   Qaug    = (u16*)(ws + alloc((size_t)8 * NF * DA * 2));
  u16*   Kaug    = (u16*)(ws + alloc((size_t)8 * NS * DA * 2));
  u16*   VT      = (u16*)(ws + alloc((size_t)8 * HD * NS * 2));
  float* kk2     = (float*)(ws + alloc((size_t)NS * 4));
  float* Opart   = (float*)(ws + alloc((size_t)2 * 8 * NF * 64 * 4));
  float2* mlb    = (float2*)(ws + alloc((size_t)2 * 8 * NF * 8));
  // aliases (producer dead before alias written)
  u16* plk_ln = plk_h;
  u16* sgf    = sxy_h;
  u16* qg_lin = plk2;
  u16* kg_lin = sxy2;

  dim3 b256(256);
  // L0: convert + ffT + silus
  k_l0<<<dim3(13793), b256, 0, stream>>>(
      pos_w2, fa_w, sa_w, wq, wk, wv, plk_w2, sxy_w2, wqg, wkg, sat_tokens,
      wpool, bk, bv, bkv, front_feat, ffT,
      bev_xy, pos_w1, pos_b1, pos_h,
      plucker, plk_w1, plk_b1, plk_h,
      sat_xy, sxy_w1, sxy_b1, sxy_h);

  // L1 GEMMs
  GP gpos {pos_h, wpool + OFF_POSW2, pos_b2, pos, 512, 512, 4096};
  GP gfeat{ffT, wpool + OFF_FAW, fa_b, feat_pre, 320, 512, 4096};
  GP gsat {wpool + OFF_SATT, wpool + OFF_SAW, sa_b, satf_pre, 768, 512, 1024};
  GP ggq1 {plk_h, wpool + OFF_PLKW2, plk_b2, plk2, 128, 128, 4096};
  GP ggk1 {sxy_h, wpool + OFF_SXYW2, sxy_b2, sxy2, 128, 128, 1024};
  k_gemm_L1<<<dim3(1312), b256, 0, stream>>>(gpos, gfeat, gsat, ggq1, ggk1);

  // LNs
  k_ln_all<<<dim3(2560), b256, 0, stream>>>(
      feat_pre, pos, fa_ln_g, fa_ln_b, qn_g, qn_b, q_embed,
      satf_pre, sa_ln_g, sa_ln_b, satf,
      plk2, sxy2, gqn_g, gqn_b, gkn_g, gkn_b, plk_ln, sgf);

  // L2 GEMMs
  GP gq  {q_embed, wpool + OFF_WQ, bq, q_lin, 512, 512, 4096};
  GP gkv {satf, wpool + OFF_WKV, bkv, kv_lin, 512, 1024, 1024};
  GP ggq2{plk_ln, wpool + OFF_WQG, bqg, qg_lin, 128, 128, 4096};
  GP ggk2{sgf, wpool + OFF_WKG, bkg, kg_lin, 128, 128, 1024};
  k_gemm_L2<<<dim3(928), b256, 0, stream>>>(gq, gkv, ggq2, ggk2);

  // prep (qk aug + vt)
  k_prep<<<dim3(10368), b256, 0, stream>>>(
      q_lin, qg_lin, bev_xy, Qaug, kv_lin, kg_lin, sat_xy, Kaug, kk2, VT);

  k_flash<<<dim3(NF / 64, 8, 2), b256, 0, stream>>>(Qaug, Kaug, VT, kk2, Opart, mlb);
  k_combine<<<dim3(NF * MD / 4 / 256), b256, 0, stream>>>(Opart, mlb, (float*)d_out);
}